// Round 3
// baseline (827.893 us; speedup 1.0000x reference)
//
#include <hip/hip_runtime.h>
#include <hip/hip_bf16.h>
#include <math.h>

#define Lr 512
#define LL (512*512)
#define PZROW 73728   // shorts per pzb row: 18 chunks * 512 cols * 8ch

typedef __bf16 bf16x8 __attribute__((ext_vector_type(8)));
typedef float f32x16 __attribute__((ext_vector_type(16)));

static __device__ __forceinline__ unsigned short f2bf(float f) {
    union { float f; unsigned u; } a; a.f = f;
    unsigned r = a.u + 0x7fff + ((a.u >> 16) & 1);
    return (unsigned short)(r >> 16);
}

static __device__ __forceinline__ unsigned pack2(float lo, float hi) {
    return (unsigned)f2bf(lo) | ((unsigned)f2bf(hi) << 16);
}

// ------------------------------- zero stats + pcbT (rows 192..194 of vpT)
__global__ __launch_bounds__(512) void zero_stats_k(float* lg_acc, float* pz_acc,
        float* vpT, const float* __restrict__ pcb) {
    int t = threadIdx.x, b = blockIdx.x;
    if (b == 0) {
        if (t < 32) lg_acc[t] = 0.f;
        if (t < 272) pz_acc[t] = 0.f;
    }
    // pcbT: vpT[(192+cc)*512 + i] = pcb[i*3+cc]
    vpT[(size_t)(192 + b) * 512 + t] = pcb[t * 3 + b];
}

// ------------------------ cp_w * rs  -> bf16 wb[o][tap*144+c]  (norm folded)
__global__ __launch_bounds__(256) void wb_prep_k(const float* __restrict__ cpw,
        const float* __restrict__ pzmr, unsigned short* __restrict__ wb) {
    int idx = blockIdx.x * 256 + threadIdx.x;
    if (idx >= 128 * 1296) return;
    int o = idx / 1296, k = idx % 1296;
    int tap = k / 144, c = k % 144;
    float v = (c < 136) ? cpw[(o * 136 + c) * 9 + tap] * pzmr[c * 2 + 1] : 0.f;
    wb[idx] = f2bf(v);
}

// ---------------- kc[o][tap] = -sum_c w[o,c,tap]*rs_c*m_c  (mean correction)
__global__ __launch_bounds__(128) void kc_prep_k(const float* __restrict__ cpw,
        const float* __restrict__ pzmr, float* __restrict__ kc) {
    int idx = blockIdx.x * 128 + threadIdx.x;
    if (idx >= 1152) return;
    int o = idx / 9, tap = idx % 9;
    float s = 0.f;
    for (int c = 0; c < 136; c++)
        s += cpw[(o * 136 + c) * 9 + tap] * pzmr[c * 2 + 1] * pzmr[c * 2];
    kc[idx] = -s;
}

// ---------------------------------------------------------------- qkv + l2g
__device__ __forceinline__ const float* qkv_colptr(const float* Wq, const float* Wk, const float* Wv, int c) {
    return c < 192 ? (Wq + c) : (c < 384 ? (Wk + c - 192) : (Wv + c - 384));
}

__global__ __launch_bounds__(256) void qkv_k(const float* __restrict__ x,
        const float* __restrict__ Wq, const float* __restrict__ Wk, const float* __restrict__ Wv,
        const float* __restrict__ R, const float* __restrict__ tv,
        float* __restrict__ qs, float* __restrict__ ks, float* __restrict__ vpT,
        float* __restrict__ q2, float* __restrict__ k2) {
    __shared__ float xrow[256];
    __shared__ float praw[576];
    __shared__ float tr[576];
    __shared__ float Rt[12];
    int i = blockIdx.x, t = threadIdx.x;
    xrow[t] = x[i * 256 + t];
    if (t < 12) Rt[t] = (t < 9) ? R[i * 9 + t] : tv[i * 3 + t - 9];
    __syncthreads();
    const float* p0 = qkv_colptr(Wq, Wk, Wv, t);
    const float* p1 = qkv_colptr(Wq, Wk, Wv, t + 256);
    const float* p2 = qkv_colptr(Wq, Wk, Wv, t < 64 ? t + 512 : 575);
    float a0 = 0.f, a1 = 0.f, a2 = 0.f;
    for (int f = 0; f < 256; f++) {
        float xv = xrow[f];
        a0 += xv * p0[f * 192];
        a1 += xv * p1[f * 192];
        a2 += xv * p2[f * 192];
    }
    praw[t] = a0; praw[t + 256] = a1;
    if (t < 64) praw[t + 512] = a2;
    __syncthreads();
    if (t < 192) {
        int seg = t / 64, pt = t % 64;
        float b0 = praw[seg * 192 + pt * 3], b1_ = praw[seg * 192 + pt * 3 + 1], b2_ = praw[seg * 192 + pt * 3 + 2];
        #pragma unroll
        for (int r = 0; r < 3; r++)
            tr[seg * 192 + pt * 3 + r] = Rt[r * 3] * b0 + Rt[r * 3 + 1] * b1_ + Rt[r * 3 + 2] * b2_ + Rt[9 + r];
    }
    __syncthreads();
    if (t < 8) {
        float s = 0.f;
        #pragma unroll
        for (int d = 0; d < 24; d++) { float v = tr[t * 24 + d]; s += v * v; }
        q2[i * 8 + t] = s;
    } else if (t < 16) {
        int h = t - 8; float s = 0.f;
        #pragma unroll
        for (int d = 0; d < 24; d++) { float v = tr[192 + h * 24 + d]; s += v * v; }
        k2[i * 8 + h] = s;
    }
    for (int f = t; f < 384; f += 256) {
        float v = tr[f];
        if (f < 192) qs[i * 192 + f] = v;
        else ks[i * 192 + f - 192] = v;
    }
    if (t < 192) vpT[(size_t)t * 512 + i] = tr[384 + t];
}

// -------------------- z channel stats + raw-bf16 pzb z-part (chunks 0..15)
__global__ __launch_bounds__(256) void zstats_pzb_k(const float4* __restrict__ z4,
        float* pz_acc, unsigned short* __restrict__ pzb) {
    __shared__ float acc[256];   // 128 ch x {sum, sumsq}
    int t = threadIdx.x;
    acc[t] = 0.f;
    __syncthreads();
    int chunk = t & 15, pl = t >> 4;
    int p0 = blockIdx.x * 128;
    float s[8], s2[8];
    #pragma unroll
    for (int u = 0; u < 8; u++) { s[u] = 0.f; s2[u] = 0.f; }
    #pragma unroll
    for (int k = 0; k < 8; k++) {
        int pos = p0 + k * 16 + pl;
        const float4* src = z4 + (size_t)pos * 32 + chunk * 2;
        float4 v0 = src[0], v1 = src[1];
        float vv[8] = {v0.x, v0.y, v0.z, v0.w, v1.x, v1.y, v1.z, v1.w};
        #pragma unroll
        for (int u = 0; u < 8; u++) { s[u] += vv[u]; s2[u] += vv[u] * vv[u]; }
        uint4 q;
        q.x = pack2(vv[0], vv[1]); q.y = pack2(vv[2], vv[3]);
        q.z = pack2(vv[4], vv[5]); q.w = pack2(vv[6], vv[7]);
        int row = pos >> 9, col = pos & 511;
        *(uint4*)(pzb + ((size_t)row * 18 + chunk) * 4096 + col * 8) = q;
    }
    #pragma unroll
    for (int u = 0; u < 8; u++) {
        atomicAdd(&acc[(chunk * 8 + u) * 2], s[u]);
        atomicAdd(&acc[(chunk * 8 + u) * 2 + 1], s2[u]);
    }
    __syncthreads();
    if (t < 128) {
        atomicAdd(&pz_acc[t * 2], acc[t * 2]);
        atomicAdd(&pz_acc[t * 2 + 1], acc[t * 2 + 1]);
    }
}

// ------------------------------------------- logits_pair + logits_spatial (lg) + stats
__global__ __launch_bounds__(256) void lg_k(const float* __restrict__ z,
        const float* __restrict__ Wp2h, const float* __restrict__ gamma,
        const float* __restrict__ qs, const float* __restrict__ ks,
        const float* __restrict__ q2, const float* __restrict__ k2,
        float* __restrict__ lg, float* lg_acc) {
    __shared__ float zl[32 * 132];
    __shared__ float wh[8 * 132];
    __shared__ float qrow[192];
    __shared__ float q2row[8];
    __shared__ float sacc[32];
    int i = blockIdx.x, t = threadIdx.x;
    for (int f = t; f < 1024; f += 256) { int h = f >> 7, p = f & 127; wh[h * 132 + p] = Wp2h[p * 8 + h]; }
    if (t < 192) qrow[t] = qs[i * 192 + t];
    if (t < 8) q2row[t] = q2[i * 8 + t];
    if (t < 32) sacc[t] = 0.f;
    int jl = t >> 3, h = t & 7;
    float gsc = -gamma[h] * 0.08333333333333333f;
    float sp = 0.f, sp2 = 0.f, ss = 0.f, ss2 = 0.f;
    __syncthreads();
    for (int jt = 0; jt < 16; jt++) {
        int j0 = jt * 32;
        const float4* zsrc = (const float4*)(z + (size_t)(i * 512 + j0) * 128);
        #pragma unroll
        for (int r = 0; r < 4; r++) {
            int idx4 = r * 256 + t;
            int zjl = idx4 >> 5, p4 = idx4 & 31;
            *(float4*)&zl[zjl * 132 + p4 * 4] = zsrc[idx4];
        }
        __syncthreads();
        int j = j0 + jl;
        float accp = 0.f;
        const float4* za = (const float4*)&zl[jl * 132];
        const float4* wa = (const float4*)&wh[h * 132];
        #pragma unroll
        for (int p4 = 0; p4 < 32; p4++) {
            float4 a = za[p4], b = wa[p4];
            accp += a.x * b.x + a.y * b.y + a.z * b.z + a.w * b.w;
        }
        const float4* kp = (const float4*)(ks + (size_t)j * 192 + h * 24);
        const float4* qp = (const float4*)&qrow[h * 24];
        float dqk = 0.f;
        #pragma unroll
        for (int d4 = 0; d4 < 6; d4++) {
            float4 a = qp[d4], b = kp[d4];
            dqk += a.x * b.x + a.y * b.y + a.z * b.z + a.w * b.w;
        }
        float ssd = q2row[h] + k2[j * 8 + h] - 2.f * dqk;
        float lgs = ssd * gsc;
        lg[(size_t)h * LL + i * 512 + j] = accp;
        lg[(size_t)(8 + h) * LL + i * 512 + j] = lgs;
        sp += accp; sp2 += accp * accp; ss += lgs; ss2 += lgs * lgs;
        __syncthreads();
    }
    atomicAdd(&sacc[h * 2], sp);        atomicAdd(&sacc[h * 2 + 1], sp2);
    atomicAdd(&sacc[16 + h * 2], ss);   atomicAdd(&sacc[16 + h * 2 + 1], ss2);
    __syncthreads();
    if (t < 16) {
        atomicAdd(&lg_acc[t * 2], sacc[t * 2]);
        atomicAdd(&lg_acc[t * 2 + 1], sacc[t * 2 + 1]);
    }
}

// ---------------------------------------------------------------- stats -> mean,rstd
__global__ void finalize_k(const float* __restrict__ acc, float* __restrict__ mr, int nch, float npix) {
    int t = threadIdx.x;
    if (t < nch) {
        float m = acc[t * 2] / npix;
        float v = acc[t * 2 + 1] / npix - m * m;
        mr[t * 2] = m;
        mr[t * 2 + 1] = rsqrtf(fmaxf(v, 0.f) + 1e-5f);
    }
}

// ----------------------------------- inorm(lg) -> conv3(16->8) -> leaky -> softmax(j)
// + emit pzb chunks 16 (alpha bf16) and 17 (zero pad)
__global__ __launch_bounds__(256) void ca_softmax_k(const float* __restrict__ lg,
        const float* __restrict__ lgmr, const float* __restrict__ caw, const float* __restrict__ cab,
        float* __restrict__ alpha, float* pz_acc, unsigned short* __restrict__ pzb) {
    __shared__ float wl[1152];
    __shared__ float mr[32];
    __shared__ float cb[8];
    __shared__ float red[64];
    int i = blockIdx.x, t = threadIdx.x;
    for (int f = t; f < 1152; f += 256) {
        int o = f & 7, k = f >> 3; int c = k / 9, r = k % 9;
        wl[f] = caw[(o * 16 + c) * 9 + r];
    }
    if (t < 32) mr[t] = lgmr[t];
    if (t < 8) cb[t] = cab[t];
    __syncthreads();
    float acc0[8], acc1[8];
    #pragma unroll
    for (int o = 0; o < 8; o++) { acc0[o] = 0.f; acc1[o] = 0.f; }
    int j0 = t, j1 = t + 256;
    const float4* w4 = (const float4*)wl;
    for (int c = 0; c < 16; c++) {
        float m = mr[c * 2], rs = mr[c * 2 + 1];
        const float* lgc = lg + (size_t)c * LL;
        #pragma unroll
        for (int di = 0; di < 3; di++) {
            int row = i - 1 + di;
            if (row < 0 || row >= 512) continue;
            const float* lr = lgc + (size_t)row * 512;
            float v0[3], v1[3];
            v0[0] = (j0 > 0) ? (lr[j0 - 1] - m) * rs : 0.f;
            v0[1] = (lr[j0] - m) * rs;
            v0[2] = (lr[j0 + 1] - m) * rs;
            v1[0] = (lr[j1 - 1] - m) * rs;
            v1[1] = (lr[j1] - m) * rs;
            v1[2] = (j1 < 511) ? (lr[j1 + 1] - m) * rs : 0.f;
            int wb = (c * 9 + di * 3) * 2;
            #pragma unroll
            for (int dj = 0; dj < 3; dj++) {
                float4 wa = w4[wb + dj * 2], wbv = w4[wb + dj * 2 + 1];
                acc0[0] += wa.x * v0[dj]; acc0[1] += wa.y * v0[dj]; acc0[2] += wa.z * v0[dj]; acc0[3] += wa.w * v0[dj];
                acc0[4] += wbv.x * v0[dj]; acc0[5] += wbv.y * v0[dj]; acc0[6] += wbv.z * v0[dj]; acc0[7] += wbv.w * v0[dj];
                acc1[0] += wa.x * v1[dj]; acc1[1] += wa.y * v1[dj]; acc1[2] += wa.z * v1[dj]; acc1[3] += wa.w * v1[dj];
                acc1[4] += wbv.x * v1[dj]; acc1[5] += wbv.y * v1[dj]; acc1[6] += wbv.z * v1[dj]; acc1[7] += wbv.w * v1[dj];
            }
        }
    }
    float s0[8], s1[8];
    #pragma unroll
    for (int o = 0; o < 8; o++) {
        float v = acc0[o] + cb[o]; s0[o] = v >= 0.f ? v : 0.01f * v;
        float w = acc1[o] + cb[o]; s1[o] = w >= 0.f ? w : 0.01f * w;
    }
    int lane = t & 63, wid = t >> 6;
    float mx[8];
    #pragma unroll
    for (int o = 0; o < 8; o++) mx[o] = fmaxf(s0[o], s1[o]);
    for (int off = 1; off < 64; off <<= 1) {
        #pragma unroll
        for (int o = 0; o < 8; o++) mx[o] = fmaxf(mx[o], __shfl_xor(mx[o], off));
    }
    if (lane == 0) {
        #pragma unroll
        for (int o = 0; o < 8; o++) red[wid * 8 + o] = mx[o];
    }
    __syncthreads();
    float M[8];
    #pragma unroll
    for (int o = 0; o < 8; o++) M[o] = fmaxf(fmaxf(red[o], red[8 + o]), fmaxf(red[16 + o], red[24 + o]));
    float e0[8], e1[8], sm[8];
    #pragma unroll
    for (int o = 0; o < 8; o++) { e0[o] = expf(s0[o] - M[o]); e1[o] = expf(s1[o] - M[o]); sm[o] = e0[o] + e1[o]; }
    __syncthreads();
    for (int off = 1; off < 64; off <<= 1) {
        #pragma unroll
        for (int o = 0; o < 8; o++) sm[o] += __shfl_xor(sm[o], off);
    }
    if (lane == 0) {
        #pragma unroll
        for (int o = 0; o < 8; o++) red[wid * 8 + o] = sm[o];
    }
    __syncthreads();
    float a0[8], a1[8], st_s[8], st_q[8];
    #pragma unroll
    for (int o = 0; o < 8; o++) {
        float rden = 1.f / (red[o] + red[8 + o] + red[16 + o] + red[24 + o]);
        a0[o] = e0[o] * rden; a1[o] = e1[o] * rden;
        st_s[o] = a0[o] + a1[o];
        st_q[o] = a0[o] * a0[o] + a1[o] * a1[o];
    }
    size_t base = (size_t)i * 512;
    #pragma unroll
    for (int o = 0; o < 8; o++) {
        alpha[(size_t)o * LL + base + t] = a0[o];
        alpha[(size_t)o * LL + base + t + 256] = a1[o];
    }
    {   // pzb chunk 16 = alpha (ch 128..135), chunk 17 = zero pad
        uint4 p0, p1;
        p0.x = pack2(a0[0], a0[1]); p0.y = pack2(a0[2], a0[3]);
        p0.z = pack2(a0[4], a0[5]); p0.w = pack2(a0[6], a0[7]);
        p1.x = pack2(a1[0], a1[1]); p1.y = pack2(a1[2], a1[3]);
        p1.z = pack2(a1[4], a1[5]); p1.w = pack2(a1[6], a1[7]);
        unsigned short* pb = pzb + (size_t)i * PZROW + 16 * 4096;
        *(uint4*)(pb + (size_t)t * 8) = p0;
        *(uint4*)(pb + (size_t)(t + 256) * 8) = p1;
        uint4 zz = {0u, 0u, 0u, 0u};
        *(uint4*)(pb + 4096 + (size_t)t * 8) = zz;
        *(uint4*)(pb + 4096 + (size_t)(t + 256) * 8) = zz;
    }
    __syncthreads();
    for (int off = 1; off < 64; off <<= 1) {
        #pragma unroll
        for (int o = 0; o < 8; o++) { st_s[o] += __shfl_xor(st_s[o], off); st_q[o] += __shfl_xor(st_q[o], off); }
    }
    if (lane == 0) {
        #pragma unroll
        for (int o = 0; o < 8; o++) { red[wid * 8 + o] = st_s[o]; red[32 + wid * 8 + o] = st_q[o]; }
    }
    __syncthreads();
    if (t < 8) {
        float ts = red[t] + red[8 + t] + red[16 + t] + red[24 + t];
        float tq = red[32 + t] + red[40 + t] + red[48 + t] + red[56 + t];
        atomicAdd(&pz_acc[(128 + t) * 2], ts);
        atomicAdd(&pz_acc[(128 + t) * 2 + 1], tq);
    }
}

// ------------- aggregation features per row i -> featg[i][1536]
// [0..1023] feat_p2n; [1024..1215] fp; [1216..1279] fn; [1280..1471] fdir;
// [1472..1495] fpb; [1496..1503] fnb; [1504..1527] fdb; [1528..1535] pad 0
__global__ __launch_bounds__(256) void aggfeat_k(
        const float* __restrict__ alpha, const float* __restrict__ z,
        const float* __restrict__ vpT,
        const float* __restrict__ R, const float* __restrict__ tv,
        float* __restrict__ featg) {
    __shared__ float al[8 * 512];
    __shared__ float zl[32 * 128];
    __shared__ float agg[216];
    __shared__ float featl[512];
    __shared__ float Rt[12];
    int i = blockIdx.x, t = threadIdx.x;
    // prefetch z chunk 0 into regs (T14)
    float4 rg[4];
    const float4* zsrc = (const float4*)(z + (size_t)i * 512 * 128);
    #pragma unroll
    for (int k = 0; k < 4; k++) rg[k] = zsrc[k * 256 + t];
    // alpha -> LDS (float4)
    #pragma unroll
    for (int f = t; f < 1024; f += 256)
        ((float4*)al)[f] = ((const float4*)(alpha + (size_t)(f >> 7) * LL + (size_t)i * 512))[f & 127];
    if (t < 12) Rt[t] = (t < 9) ? R[i * 9 + t] : tv[i * 3 + t - 9];
    int hh = t >> 5, p4 = t & 31;
    float4 accp = {0.f, 0.f, 0.f, 0.f};
    for (int jc = 0; jc < 16; jc++) {
        #pragma unroll
        for (int k = 0; k < 4; k++) ((float4*)zl)[k * 256 + t] = rg[k];
        __syncthreads();
        if (jc < 15) {
            const float4* zn = zsrc + (size_t)(jc + 1) * 1024;
            #pragma unroll
            for (int k = 0; k < 4; k++) rg[k] = zn[k * 256 + t];
        }
        const float* ar = al + hh * 512 + jc * 32;
        const float4* zv = (const float4*)zl + p4;
        #pragma unroll 8
        for (int jl = 0; jl < 32; jl++) {
            float a = ar[jl];
            float4 v = zv[jl * 32];
            accp.x += a * v.x; accp.y += a * v.y; accp.z += a * v.z; accp.w += a * v.w;
        }
        __syncthreads();
    }
    // feat_p2n direct store (index t*4 == hh*128 + p4*4)
    *(float4*)(featg + (size_t)i * 1536 + t * 4) = accp;
    // agg: 216 dot-products, contiguous vpT rows
    if (t < 216) {
        const float* src; int h;
        if (t < 192) { src = vpT + (size_t)t * 512; h = t / 24; }
        else { int u = t - 192; src = vpT + (size_t)(192 + u % 3) * 512; h = u / 3; }
        const float4* s4 = (const float4*)src;
        const float4* a4 = (const float4*)(al + h * 512);
        float acc = 0.f;
        #pragma unroll 8
        for (int k = 0; k < 128; k++) {
            float4 a = a4[k], b = s4[k];
            acc += a.x * b.x + a.y * b.y + a.z * b.z + a.w * b.w;
        }
        agg[t] = acc;
    }
    __syncthreads();
    // geometric transforms into featl (offset-1024 layout)
    if (t < 64) {
        int h = t >> 3, v = t & 7;
        float d0 = agg[h * 24 + v * 3] - Rt[9];
        float d1 = agg[h * 24 + v * 3 + 1] - Rt[10];
        float d2 = agg[h * 24 + v * 3 + 2] - Rt[11];
        float f0 = Rt[0] * d0 + Rt[3] * d1 + Rt[6] * d2;
        float f1 = Rt[1] * d0 + Rt[4] * d1 + Rt[7] * d2;
        float f2 = Rt[2] * d0 + Rt[5] * d1 + Rt[8] * d2;
        float n = sqrtf(f0 * f0 + f1 * f1 + f2 * f2);
        float rn = 1.f / (n + 1e-6f);
        featl[h * 24 + v * 3] = f0;
        featl[h * 24 + v * 3 + 1] = f1;
        featl[h * 24 + v * 3 + 2] = f2;
        featl[192 + h * 8 + v] = n;
        featl[256 + h * 24 + v * 3] = f0 * rn;
        featl[256 + h * 24 + v * 3 + 1] = f1 * rn;
        featl[256 + h * 24 + v * 3 + 2] = f2 * rn;
    } else if (t < 72) {
        int h = t - 64;
        float d0 = agg[192 + h * 3] - Rt[9];
        float d1 = agg[192 + h * 3 + 1] - Rt[10];
        float d2 = agg[192 + h * 3 + 2] - Rt[11];
        float f0 = Rt[0] * d0 + Rt[3] * d1 + Rt[6] * d2;
        float f1 = Rt[1] * d0 + Rt[4] * d1 + Rt[7] * d2;
        float f2 = Rt[2] * d0 + Rt[5] * d1 + Rt[8] * d2;
        float n = sqrtf(f0 * f0 + f1 * f1 + f2 * f2);
        float rn = 1.f / (n + 1e-6f);
        featl[448 + h * 3] = f0; featl[448 + h * 3 + 1] = f1; featl[448 + h * 3 + 2] = f2;
        featl[472 + h] = n;
        featl[480 + h * 3] = f0 * rn; featl[480 + h * 3 + 1] = f1 * rn; featl[480 + h * 3 + 2] = f2 * rn;
    } else if (t < 80) {
        featl[432 + t] = 0.f;   // pad 504..511
    }
    __syncthreads();
    if (t < 128)
        ((float4*)(featg + (size_t)i * 1536 + 1024))[t] = ((const float4*)featl)[t];
}

// ------------- MLP: h1 = leaky(LN(feat@W1+b1)); fa = h1@W2+b2; xout = LN(x+fa)
// 256 blocks x 2 rows: W1 streamed once per block (coalesced), feat/h1 broadcast.
__global__ __launch_bounds__(256) void mlp_k(
        const float* __restrict__ featg,
        const float* __restrict__ W1, const float* __restrict__ b1,
        const float* __restrict__ ln1g, const float* __restrict__ ln1b,
        const float* __restrict__ W2, const float* __restrict__ b2,
        const float* __restrict__ lng, const float* __restrict__ lnb,
        const float* __restrict__ x, float* __restrict__ xout) {
    __shared__ float fl[2][1528];
    __shared__ float h1[2][512];
    __shared__ float red[16];
    int b = blockIdx.x, t = threadIdx.x;
    int i0 = b * 2;
    for (int f = t; f < 764; f += 256) {
        int r = f / 382, k = f - r * 382;
        ((float4*)fl[r])[k] = ((const float4*)(featg + (size_t)(i0 + r) * 1536))[k];
    }
    __syncthreads();
    float a00 = b1[t], a01 = b1[t + 256];
    float a10 = a00, a11 = a01;
    for (int k = 0; k < 1528; k += 4) {
        float4 f0 = *(const float4*)&fl[0][k];
        float4 f1 = *(const float4*)&fl[1][k];
        const float* w = W1 + (size_t)k * 512 + t;
        float w0 = w[0], w1 = w[512], w2 = w[1024], w3 = w[1536];
        float v0 = w[256], v1 = w[768], v2 = w[1280], v3 = w[1792];
        a00 += f0.x * w0 + f0.y * w1 + f0.z * w2 + f0.w * w3;
        a01 += f0.x * v0 + f0.y * v1 + f0.z * v2 + f0.w * v3;
        a10 += f1.x * w0 + f1.y * w1 + f1.z * w2 + f1.w * w3;
        a11 += f1.x * v0 + f1.y * v1 + f1.z * v2 + f1.w * v3;
    }
    int lane = t & 63, wid = t >> 6;
    float s0 = a00 + a01, q0 = a00 * a00 + a01 * a01;
    float s1 = a10 + a11, q1 = a10 * a10 + a11 * a11;
    for (int off = 1; off < 64; off <<= 1) {
        s0 += __shfl_xor(s0, off); q0 += __shfl_xor(q0, off);
        s1 += __shfl_xor(s1, off); q1 += __shfl_xor(q1, off);
    }
    if (lane == 0) { red[wid * 4] = s0; red[wid * 4 + 1] = q0; red[wid * 4 + 2] = s1; red[wid * 4 + 3] = q1; }
    __syncthreads();
    float S0 = red[0] + red[4] + red[8] + red[12], Q0 = red[1] + red[5] + red[9] + red[13];
    float S1 = red[2] + red[6] + red[10] + red[14], Q1 = red[3] + red[7] + red[11] + red[15];
    float m0 = S0 / 512.f, r0 = rsqrtf(fmaxf(Q0 / 512.f - m0 * m0, 0.f) + 1e-5f);
    float m1 = S1 / 512.f, r1 = rsqrtf(fmaxf(Q1 / 512.f - m1 * m1, 0.f) + 1e-5f);
    float g0 = ln1g[t], g1 = ln1g[t + 256], bb0 = ln1b[t], bb1 = ln1b[t + 256];
    float h00 = (a00 - m0) * r0 * g0 + bb0; h00 = h00 >= 0.f ? h00 : 0.01f * h00;
    float h01 = (a01 - m0) * r0 * g1 + bb1; h01 = h01 >= 0.f ? h01 : 0.01f * h01;
    float h10 = (a10 - m1) * r1 * g0 + bb0; h10 = h10 >= 0.f ? h10 : 0.01f * h10;
    float h11 = (a11 - m1) * r1 * g1 + bb1; h11 = h11 >= 0.f ? h11 : 0.01f * h11;
    h1[0][t] = h00; h1[0][t + 256] = h01; h1[1][t] = h10; h1[1][t + 256] = h11;
    __syncthreads();
    float c0 = b2[t], c1 = c0;
    for (int k = 0; k < 512; k += 4) {
        float4 hv0 = *(const float4*)&h1[0][k];
        float4 hv1 = *(const float4*)&h1[1][k];
        const float* w = W2 + (size_t)k * 256 + t;
        float w0 = w[0], w1 = w[256], w2 = w[512], w3 = w[768];
        c0 += hv0.x * w0 + hv0.y * w1 + hv0.z * w2 + hv0.w * w3;
        c1 += hv1.x * w0 + hv1.y * w1 + hv1.z * w2 + hv1.w * w3;
    }
    float xv0 = x[(size_t)i0 * 256 + t] + c0;
    float xv1 = x[(size_t)(i0 + 1) * 256 + t] + c1;
    float ss0 = xv0, qq0 = xv0 * xv0, ss1 = xv1, qq1 = xv1 * xv1;
    for (int off = 1; off < 64; off <<= 1) {
        ss0 += __shfl_xor(ss0, off); qq0 += __shfl_xor(qq0, off);
        ss1 += __shfl_xor(ss1, off); qq1 += __shfl_xor(qq1, off);
    }
    __syncthreads();
    if (lane == 0) { red[wid * 4] = ss0; red[wid * 4 + 1] = qq0; red[wid * 4 + 2] = ss1; red[wid * 4 + 3] = qq1; }
    __syncthreads();
    float Sx0 = red[0] + red[4] + red[8] + red[12], Qx0 = red[1] + red[5] + red[9] + red[13];
    float Sx1 = red[2] + red[6] + red[10] + red[14], Qx1 = red[3] + red[7] + red[11] + red[15];
    float mx0 = Sx0 / 256.f, rx0 = rsqrtf(fmaxf(Qx0 / 256.f - mx0 * mx0, 0.f) + 1e-5f);
    float mx1 = Sx1 / 256.f, rx1 = rsqrtf(fmaxf(Qx1 / 256.f - mx1 * mx1, 0.f) + 1e-5f);
    xout[(size_t)i0 * 256 + t] = (xv0 - mx0) * rx0 * lng[t] + lnb[t];
    xout[(size_t)(i0 + 1) * 256 + t] = (xv1 - mx1) * rx1 * lng[t] + lnb[t];
}

// ---------------- conv3(136->128) on precomputed raw-bf16 pzb, norm folded into wb.
// T14 staging + LDS-transposed coalesced float4 epilogue stores.
__global__ __launch_bounds__(256) void conv_mfma_k(
        const unsigned short* __restrict__ pzb, const unsigned short* __restrict__ wb,
        const float* __restrict__ kc, const float* __restrict__ cpb,
        float* __restrict__ pout) {
    __shared__ unsigned short abuf[2368 * 8];   // 18*130 = 2340 used 16B slots (>= 32KB f32 staging)
    __shared__ float csA[128];
    __shared__ float cs0[128];
    __shared__ float cs2[128];
    int t = threadIdx.x;
    int bid = blockIdx.x;
    int swz = (bid & 7) * 256 + (bid >> 3);     // bijective XCD swizzle (2048 % 8 == 0)
    int i = swz >> 2;
    int j0 = (swz & 3) * 128;
    if (t < 128) {
        int o = t;
        float a0 = 0.f, a1 = 0.f, a2 = 0.f;
        #pragma unroll
        for (int di = 0; di < 3; di++) {
            int grow = i - 1 + di;
            if (grow < 0 || grow > 511) continue;
            a0 += kc[o * 9 + di * 3];
            a1 += kc[o * 9 + di * 3 + 1];
            a2 += kc[o * 9 + di * 3 + 2];
        }
        cs0[o] = a0; cs2[o] = a2; csA[o] = cpb[o] + a0 + a1 + a2;
    }
    int w = t >> 6, lane = t & 63;
    int l31 = lane & 31, lhi = lane >> 5;
    int mt0 = (w & 1) * 64;      // wave's m base
    int nt0 = (w >> 1) * 64;     // wave's n base

    uint4 rg[10];
    #define STAGE_LOAD(DI) do {                                                \
        int grow_ = i - 1 + (DI);                                              \
        bool rowok_ = (grow_ >= 0 && grow_ < 512);                             \
        const unsigned short* rowp_ = pzb + (size_t)grow_ * PZROW;             \
        _Pragma("unroll")                                                      \
        for (int k = 0; k < 10; k++) {                                         \
            int f_ = t + k * 256;                                              \
            uint4 v_ = {0u, 0u, 0u, 0u};                                       \
            if (f_ < 2340) {                                                   \
                int c_ = f_ / 130, col_ = f_ - c_ * 130;                       \
                int gcol_ = j0 - 1 + col_;                                     \
                if (rowok_ && (unsigned)gcol_ < 512u)                          \
                    v_ = *(const uint4*)(rowp_ + c_ * 4096 + gcol_ * 8);       \
            }                                                                  \
            rg[k] = v_;                                                        \
        }                                                                      \
    } while (0)

    #define STAGE_WRITE() do {                                                 \
        _Pragma("unroll")                                                      \
        for (int k = 0; k < 10; k++) {                                         \
            int f_ = t + k * 256;                                              \
            if (f_ < 2340) *(uint4*)(abuf + f_ * 8) = rg[k];                   \
        }                                                                      \
    } while (0)

    f32x16 acc00 = {}, acc01 = {}, acc10 = {}, acc11 = {};

    STAGE_LOAD(0);
    STAGE_WRITE();
    __syncthreads();

    #pragma unroll
    for (int di = 0; di < 3; di++) {
        if (di < 2) STAGE_LOAD(di + 1);
        #pragma unroll
        for (int dj = 0; dj < 3; dj++) {
            int tap = di * 3 + dj;
            const unsigned short* wp0 = wb + (size_t)(nt0 + l31) * 1296 + tap * 144 + lhi * 8;
            const unsigned short* wp1 = wp0 + 32 * 1296;
            const unsigned short* ap0 = abuf + lhi * 1040 + (mt0 + l31 + dj) * 8;
            const unsigned short* ap1 = ap0 + 256;
            #pragma unroll
            for (int ksn = 0; ksn < 9; ksn++) {
                bf16x8 a0 = *(const bf16x8*)(ap0 + ksn * 2080);
                bf16x8 a1 = *(const bf16x8*)(ap1 + ksn * 2080);
                bf16x8 b0 = *(const bf16x8*)(wp0 + ksn * 16);
                bf16x8 b1 = *(const bf16x8*)(wp1 + ksn * 16);
                acc00 = __builtin_amdgcn_mfma_f32_32x32x16_bf16(a0, b0, acc00, 0, 0, 0);
                acc01 = __builtin_amdgcn_mfma_f32_32x32x16_bf16(a0, b1, acc01, 0, 0, 0);
                acc10 = __builtin_amdgcn_mfma_f32_32x32x16_bf16(a1, b0, acc10, 0, 0, 0);
                acc11 = __builtin_amdgcn_mfma_f32_32x32x16_bf16(a1, b1, acc11, 0, 0, 0);
            }
        }
        __syncthreads();
        if (di < 2) {
            STAGE_WRITE();
            __syncthreads();
        }
    }
    #undef STAGE_LOAD
    #undef STAGE_WRITE

    // ---- epilogue: bias + leaky -> LDS [64 rows][128 ch] -> coalesced float4 stores
    float* fb = (float*)abuf;
    #pragma unroll
    for (int mh = 0; mh < 2; mh++) {
        if ((w & 1) == mh) {
            #pragma unroll
            for (int mi = 0; mi < 2; mi++) {
                #pragma unroll
                for (int ni = 0; ni < 2; ni++) {
                    const f32x16* a = (mi == 0) ? (ni == 0 ? &acc00 : &acc01) : (ni == 0 ? &acc10 : &acc11);
                    int nb = nt0 + ni * 32 + l31;
                    float bA = csA[nb], b0_ = cs0[nb], b2_ = cs2[nb];
                    #pragma unroll
                    for (int r = 0; r < 16; r++) {
                        int ml = mi * 32 + 4 * lhi + (r & 3) + 8 * (r >> 2);
                        int j = j0 + mh * 64 + ml;
                        float bias = bA - (j == 0 ? b0_ : 0.f) - (j == 511 ? b2_ : 0.f);
                        float v = (*a)[r] + bias;
                        v = v >= 0.f ? v : 0.01f * v;
                        fb[ml * 128 + nb] = v;
                    }
                }
            }
        }
        __syncthreads();
        const float4* fb4 = (const float4*)fb;
        float4* gdst = (float4*)(pout + ((size_t)(i * 512 + j0 + mh * 64)) * 128);
        #pragma unroll
        for (int k = 0; k < 8; k++) {
            int f4i = k * 256 + t;
            gdst[f4i] = fb4[f4i];
        }
        __syncthreads();
    }
}

// ---------------------------------------------------------------- launcher
extern "C" void kernel_launch(void* const* d_in, const int* in_sizes, int n_in,
                              void* d_out, int out_size, void* d_ws, size_t ws_size,
                              hipStream_t stream) {
    (void)in_sizes; (void)n_in; (void)out_size; (void)ws_size;
    const float* R    = (const float*)d_in[0];
    const float* tv   = (const float*)d_in[1];
    const float* pcb  = (const float*)d_in[2];
    const float* x    = (const float*)d_in[3];
    const float* z    = (const float*)d_in[4];
    const float* wp2h = (const float*)d_in[5];
    const float* gamma= (const float*)d_in[6];
    const float* Wq   = (const float*)d_in[7];
    const float* Wk   = (const float*)d_in[8];
    const float* Wv   = (const float*)d_in[9];
    const float* W1   = (const float*)d_in[10];
    const float* b1   = (const float*)d_in[11];
    const float* ln1g = (const float*)d_in[12];
    const float* ln1b = (const float*)d_in[13];
    const float* W2   = (const float*)d_in[14];
    const float* b2   = (const float*)d_in[15];
    const float* caw  = (const float*)d_in[16];
    const float* cab  = (const float*)d_in[17];
    const float* lng  = (const float*)d_in[18];
    const float* lnb  = (const float*)d_in[19];
    const float* cpw  = (const float*)d_in[20];
    const float* cpb  = (const float*)d_in[21];

    float* ws = (float*)d_ws;
    float* qs     = ws;                  // 98304
    float* ksv    = qs + 98304;          // 98304
    float* vpT    = ksv + 98304;         // 100352 (195*512 used)
    float* q2     = vpT + 100352;        // 4096
    float* k2     = q2 + 4096;           // 4096
    float* lg_acc = k2 + 4096;           // 32
    float* lg_mr  = lg_acc + 32;         // 32
    float* pz_acc = lg_mr + 32;          // 272
    float* pz_mr  = pz_acc + 272;        // 272
    float* kc     = pz_mr + 272;         // 1152
    unsigned short* wbq = (unsigned short*)(kc + 1152);     // 82944 floats
    float* featg  = kc + 1152 + 82944;                      // 512*1536 = 786432
    float* lg     = featg + 786432;                         // 16*LL
    float* alpha  = lg + 16 * LL;                           // 8*LL
    unsigned short* pzb = (unsigned short*)(alpha + 8 * LL);// 512*73728 bf16

    float* xout = (float*)d_out;
    float* pout = xout + 131072;

    hipLaunchKernelGGL(zero_stats_k, dim3(3), dim3(512), 0, stream, lg_acc, pz_acc, vpT, pcb);
    hipLaunchKernelGGL(qkv_k, dim3(512), dim3(256), 0, stream, x, Wq, Wk, Wv, R, tv, qs, ksv, vpT, q2, k2);
    hipLaunchKernelGGL(zstats_pzb_k, dim3(2048), dim3(256), 0, stream, (const float4*)z, pz_acc, pzb);
    hipLaunchKernelGGL(lg_k, dim3(512), dim3(256), 0, stream, z, wp2h, gamma, qs, ksv, q2, k2, lg, lg_acc);
    hipLaunchKernelGGL(finalize_k, dim3(1), dim3(64), 0, stream, lg_acc, lg_mr, 16, 262144.f);
    hipLaunchKernelGGL(ca_softmax_k, dim3(512), dim3(256), 0, stream, lg, lg_mr, caw, cab, alpha, pz_acc, pzb);
    hipLaunchKernelGGL(finalize_k, dim3(1), dim3(192), 0, stream, pz_acc, pz_mr, 136, 262144.f);
    hipLaunchKernelGGL(wb_prep_k, dim3(648), dim3(256), 0, stream, cpw, pz_mr, wbq);
    hipLaunchKernelGGL(kc_prep_k, dim3(9), dim3(128), 0, stream, cpw, pz_mr, kc);
    hipLaunchKernelGGL(aggfeat_k, dim3(512), dim3(256), 0, stream, alpha, z, vpT, R, tv, featg);
    hipLaunchKernelGGL(mlp_k, dim3(256), dim3(256), 0, stream,
                       featg, W1, b1, ln1g, ln1b, W2, b2, lng, lnb, x, xout);
    hipLaunchKernelGGL(conv_mfma_k, dim3(2048), dim3(256), 0, stream, pzb, wbq, kc, cpb, pout);
}

// Round 5
// 773.685 us; speedup vs baseline: 1.0701x; 1.0701x over previous
//
#include <hip/hip_runtime.h>
#include <hip/hip_bf16.h>
#include <math.h>

#define Lr 512
#define LL (512*512)
#define PZROW 73728   // shorts per pzb row: 18 chunks * 512 cols * 8ch

typedef __bf16 bf16x8 __attribute__((ext_vector_type(8)));
typedef float f32x16 __attribute__((ext_vector_type(16)));

static __device__ __forceinline__ unsigned short f2bf(float f) {
    union { float f; unsigned u; } a; a.f = f;
    unsigned r = a.u + 0x7fff + ((a.u >> 16) & 1);
    return (unsigned short)(r >> 16);
}

static __device__ __forceinline__ unsigned pack2(float lo, float hi) {
    return (unsigned)f2bf(lo) | ((unsigned)f2bf(hi) << 16);
}

// ---------------------------------------------------------------- zero stats
__global__ __launch_bounds__(512) void zero_stats_k(float* lg_acc, float* pz_acc) {
    int t = threadIdx.x;
    if (t < 32) lg_acc[t] = 0.f;
    if (t < 272) pz_acc[t] = 0.f;
}

// ------ cp_w * rs -> bf16 wbT[tap][ksn][lhi][n][8k]  (norm folded, COALESCED)
// wbT[(((tap*9+ksn)*2+lhi)*128+n)*8 + j] = w_norm[n][ksn*16+lhi*8+j] for tap
__global__ __launch_bounds__(256) void wb_prep_k(const float* __restrict__ cpw,
        const float* __restrict__ pzmr, unsigned short* __restrict__ wb) {
    int idx = blockIdx.x * 256 + threadIdx.x;
    if (idx >= 128 * 1296) return;
    int j = idx & 7;
    int n = (idx >> 3) & 127;
    int rest = idx >> 10;
    int lhi = rest & 1;
    int ksn = (rest >> 1) % 9;
    int tap = rest / 18;
    int c = ksn * 16 + lhi * 8 + j;
    float v = (c < 136) ? cpw[(n * 136 + c) * 9 + tap] * pzmr[c * 2 + 1] : 0.f;
    wb[idx] = f2bf(v);
}

// ---------------- kc[o][tap] = -sum_c w[o,c,tap]*rs_c*m_c  (mean correction)
__global__ __launch_bounds__(128) void kc_prep_k(const float* __restrict__ cpw,
        const float* __restrict__ pzmr, float* __restrict__ kc) {
    int idx = blockIdx.x * 128 + threadIdx.x;
    if (idx >= 1152) return;
    int o = idx / 9, tap = idx % 9;
    float s = 0.f;
    for (int c = 0; c < 136; c++)
        s += cpw[(o * 136 + c) * 9 + tap] * pzmr[c * 2 + 1] * pzmr[c * 2];
    kc[idx] = -s;
}

// ---------------------------------------------------------------- qkv + l2g
__device__ __forceinline__ const float* qkv_colptr(const float* Wq, const float* Wk, const float* Wv, int c) {
    return c < 192 ? (Wq + c) : (c < 384 ? (Wk + c - 192) : (Wv + c - 384));
}

__global__ __launch_bounds__(256) void qkv_k(const float* __restrict__ x,
        const float* __restrict__ Wq, const float* __restrict__ Wk, const float* __restrict__ Wv,
        const float* __restrict__ R, const float* __restrict__ tv,
        float* __restrict__ qs, float* __restrict__ ks, float* __restrict__ vp,
        float* __restrict__ q2, float* __restrict__ k2) {
    __shared__ float xrow[256];
    __shared__ float praw[576];
    __shared__ float tr[576];
    __shared__ float Rt[12];
    int i = blockIdx.x, t = threadIdx.x;
    xrow[t] = x[i * 256 + t];
    if (t < 12) Rt[t] = (t < 9) ? R[i * 9 + t] : tv[i * 3 + t - 9];
    __syncthreads();
    const float* p0 = qkv_colptr(Wq, Wk, Wv, t);
    const float* p1 = qkv_colptr(Wq, Wk, Wv, t + 256);
    const float* p2 = qkv_colptr(Wq, Wk, Wv, t < 64 ? t + 512 : 575);
    float a0 = 0.f, a1 = 0.f, a2 = 0.f;
    for (int f = 0; f < 256; f++) {
        float xv = xrow[f];
        a0 += xv * p0[f * 192];
        a1 += xv * p1[f * 192];
        a2 += xv * p2[f * 192];
    }
    praw[t] = a0; praw[t + 256] = a1;
    if (t < 64) praw[t + 512] = a2;
    __syncthreads();
    if (t < 192) {
        int seg = t / 64, pt = t % 64;
        float b0 = praw[seg * 192 + pt * 3], b1_ = praw[seg * 192 + pt * 3 + 1], b2_ = praw[seg * 192 + pt * 3 + 2];
        #pragma unroll
        for (int r = 0; r < 3; r++)
            tr[seg * 192 + pt * 3 + r] = Rt[r * 3] * b0 + Rt[r * 3 + 1] * b1_ + Rt[r * 3 + 2] * b2_ + Rt[9 + r];
    }
    __syncthreads();
    if (t < 8) {
        float s = 0.f;
        #pragma unroll
        for (int d = 0; d < 24; d++) { float v = tr[t * 24 + d]; s += v * v; }
        q2[i * 8 + t] = s;
    } else if (t < 16) {
        int h = t - 8; float s = 0.f;
        #pragma unroll
        for (int d = 0; d < 24; d++) { float v = tr[192 + h * 24 + d]; s += v * v; }
        k2[i * 8 + h] = s;
    }
    for (int f = t; f < 576; f += 256) {
        float v = tr[f];
        if (f < 192) qs[i * 192 + f] = v;
        else if (f < 384) ks[i * 192 + f - 192] = v;
        else vp[i * 192 + f - 384] = v;
    }
}

// -------------------- z channel stats + raw-bf16 pzb z-part (chunks 0..15)
__global__ __launch_bounds__(256) void zstats_pzb_k(const float4* __restrict__ z4,
        float* pz_acc, unsigned short* __restrict__ pzb) {
    __shared__ float acc[256];   // 128 ch x {sum, sumsq}
    int t = threadIdx.x;
    acc[t] = 0.f;
    __syncthreads();
    int chunk = t & 15, pl = t >> 4;
    int p0 = blockIdx.x * 128;
    float s[8], s2[8];
    #pragma unroll
    for (int u = 0; u < 8; u++) { s[u] = 0.f; s2[u] = 0.f; }
    #pragma unroll
    for (int k = 0; k < 8; k++) {
        int pos = p0 + k * 16 + pl;
        const float4* src = z4 + (size_t)pos * 32 + chunk * 2;
        float4 v0 = src[0], v1 = src[1];
        float vv[8] = {v0.x, v0.y, v0.z, v0.w, v1.x, v1.y, v1.z, v1.w};
        #pragma unroll
        for (int u = 0; u < 8; u++) { s[u] += vv[u]; s2[u] += vv[u] * vv[u]; }
        uint4 q;
        q.x = pack2(vv[0], vv[1]); q.y = pack2(vv[2], vv[3]);
        q.z = pack2(vv[4], vv[5]); q.w = pack2(vv[6], vv[7]);
        int row = pos >> 9, col = pos & 511;
        *(uint4*)(pzb + ((size_t)row * 18 + chunk) * 4096 + col * 8) = q;
    }
    #pragma unroll
    for (int u = 0; u < 8; u++) {
        atomicAdd(&acc[(chunk * 8 + u) * 2], s[u]);
        atomicAdd(&acc[(chunk * 8 + u) * 2 + 1], s2[u]);
    }
    __syncthreads();
    if (t < 128) {
        atomicAdd(&pz_acc[t * 2], acc[t * 2]);
        atomicAdd(&pz_acc[t * 2 + 1], acc[t * 2 + 1]);
    }
}

// ------------------------------------------- logits_pair + logits_spatial (lg) + stats
__global__ __launch_bounds__(256) void lg_k(const float* __restrict__ z,
        const float* __restrict__ Wp2h, const float* __restrict__ gamma,
        const float* __restrict__ qs, const float* __restrict__ ks,
        const float* __restrict__ q2, const float* __restrict__ k2,
        float* __restrict__ lg, float* lg_acc) {
    __shared__ float zl[32 * 132];
    __shared__ float wh[8 * 132];
    __shared__ float qrow[192];
    __shared__ float q2row[8];
    __shared__ float sacc[32];
    int i = blockIdx.x, t = threadIdx.x;
    for (int f = t; f < 1024; f += 256) { int h = f >> 7, p = f & 127; wh[h * 132 + p] = Wp2h[p * 8 + h]; }
    if (t < 192) qrow[t] = qs[i * 192 + t];
    if (t < 8) q2row[t] = q2[i * 8 + t];
    if (t < 32) sacc[t] = 0.f;
    int jl = t >> 3, h = t & 7;
    float gsc = -gamma[h] * 0.08333333333333333f;
    float sp = 0.f, sp2 = 0.f, ss = 0.f, ss2 = 0.f;
    __syncthreads();
    for (int jt = 0; jt < 16; jt++) {
        int j0 = jt * 32;
        const float4* zsrc = (const float4*)(z + (size_t)(i * 512 + j0) * 128);
        #pragma unroll
        for (int r = 0; r < 4; r++) {
            int idx4 = r * 256 + t;
            int zjl = idx4 >> 5, p4 = idx4 & 31;
            *(float4*)&zl[zjl * 132 + p4 * 4] = zsrc[idx4];
        }
        __syncthreads();
        int j = j0 + jl;
        float accp = 0.f;
        const float4* za = (const float4*)&zl[jl * 132];
        const float4* wa = (const float4*)&wh[h * 132];
        #pragma unroll
        for (int p4 = 0; p4 < 32; p4++) {
            float4 a = za[p4], b = wa[p4];
            accp += a.x * b.x + a.y * b.y + a.z * b.z + a.w * b.w;
        }
        const float4* kp = (const float4*)(ks + (size_t)j * 192 + h * 24);
        const float4* qp = (const float4*)&qrow[h * 24];
        float dqk = 0.f;
        #pragma unroll
        for (int d4 = 0; d4 < 6; d4++) {
            float4 a = qp[d4], b = kp[d4];
            dqk += a.x * b.x + a.y * b.y + a.z * b.z + a.w * b.w;
        }
        float ssd = q2row[h] + k2[j * 8 + h] - 2.f * dqk;
        float lgs = ssd * gsc;
        lg[(size_t)h * LL + i * 512 + j] = accp;
        lg[(size_t)(8 + h) * LL + i * 512 + j] = lgs;
        sp += accp; sp2 += accp * accp; ss += lgs; ss2 += lgs * lgs;
        __syncthreads();
    }
    atomicAdd(&sacc[h * 2], sp);        atomicAdd(&sacc[h * 2 + 1], sp2);
    atomicAdd(&sacc[16 + h * 2], ss);   atomicAdd(&sacc[16 + h * 2 + 1], ss2);
    __syncthreads();
    if (t < 16) {
        atomicAdd(&lg_acc[t * 2], sacc[t * 2]);
        atomicAdd(&lg_acc[t * 2 + 1], sacc[t * 2 + 1]);
    }
}

// ---------------------------------------------------------------- stats -> mean,rstd
__global__ void finalize_k(const float* __restrict__ acc, float* __restrict__ mr, int nch, float npix) {
    int t = threadIdx.x;
    if (t < nch) {
        float m = acc[t * 2] / npix;
        float v = acc[t * 2 + 1] / npix - m * m;
        mr[t * 2] = m;
        mr[t * 2 + 1] = rsqrtf(fmaxf(v, 0.f) + 1e-5f);
    }
}

// ----------------------------------- inorm(lg) -> conv3(16->8) -> leaky -> softmax(j)
// + emit pzb chunks 16 (alpha bf16) and 17 (zero pad)
__global__ __launch_bounds__(256) void ca_softmax_k(const float* __restrict__ lg,
        const float* __restrict__ lgmr, const float* __restrict__ caw, const float* __restrict__ cab,
        float* __restrict__ alpha, float* pz_acc, unsigned short* __restrict__ pzb) {
    __shared__ float wl[1152];
    __shared__ float mr[32];
    __shared__ float cb[8];
    __shared__ float red[64];
    int i = blockIdx.x, t = threadIdx.x;
    for (int f = t; f < 1152; f += 256) {
        int o = f & 7, k = f >> 3; int c = k / 9, r = k % 9;
        wl[f] = caw[(o * 16 + c) * 9 + r];
    }
    if (t < 32) mr[t] = lgmr[t];
    if (t < 8) cb[t] = cab[t];
    __syncthreads();
    float acc0[8], acc1[8];
    #pragma unroll
    for (int o = 0; o < 8; o++) { acc0[o] = 0.f; acc1[o] = 0.f; }
    int j0 = t, j1 = t + 256;
    const float4* w4 = (const float4*)wl;
    for (int c = 0; c < 16; c++) {
        float m = mr[c * 2], rs = mr[c * 2 + 1];
        const float* lgc = lg + (size_t)c * LL;
        #pragma unroll
        for (int di = 0; di < 3; di++) {
            int row = i - 1 + di;
            if (row < 0 || row >= 512) continue;
            const float* lr = lgc + (size_t)row * 512;
            float v0[3], v1[3];
            v0[0] = (j0 > 0) ? (lr[j0 - 1] - m) * rs : 0.f;
            v0[1] = (lr[j0] - m) * rs;
            v0[2] = (lr[j0 + 1] - m) * rs;
            v1[0] = (lr[j1 - 1] - m) * rs;
            v1[1] = (lr[j1] - m) * rs;
            v1[2] = (j1 < 511) ? (lr[j1 + 1] - m) * rs : 0.f;
            int wb = (c * 9 + di * 3) * 2;
            #pragma unroll
            for (int dj = 0; dj < 3; dj++) {
                float4 wa = w4[wb + dj * 2], wbv = w4[wb + dj * 2 + 1];
                acc0[0] += wa.x * v0[dj]; acc0[1] += wa.y * v0[dj]; acc0[2] += wa.z * v0[dj]; acc0[3] += wa.w * v0[dj];
                acc0[4] += wbv.x * v0[dj]; acc0[5] += wbv.y * v0[dj]; acc0[6] += wbv.z * v0[dj]; acc0[7] += wbv.w * v0[dj];
                acc1[0] += wa.x * v1[dj]; acc1[1] += wa.y * v1[dj]; acc1[2] += wa.z * v1[dj]; acc1[3] += wa.w * v1[dj];
                acc1[4] += wbv.x * v1[dj]; acc1[5] += wbv.y * v1[dj]; acc1[6] += wbv.z * v1[dj]; acc1[7] += wbv.w * v1[dj];
            }
        }
    }
    float s0[8], s1[8];
    #pragma unroll
    for (int o = 0; o < 8; o++) {
        float v = acc0[o] + cb[o]; s0[o] = v >= 0.f ? v : 0.01f * v;
        float w = acc1[o] + cb[o]; s1[o] = w >= 0.f ? w : 0.01f * w;
    }
    int lane = t & 63, wid = t >> 6;
    float mx[8];
    #pragma unroll
    for (int o = 0; o < 8; o++) mx[o] = fmaxf(s0[o], s1[o]);
    for (int off = 1; off < 64; off <<= 1) {
        #pragma unroll
        for (int o = 0; o < 8; o++) mx[o] = fmaxf(mx[o], __shfl_xor(mx[o], off));
    }
    if (lane == 0) {
        #pragma unroll
        for (int o = 0; o < 8; o++) red[wid * 8 + o] = mx[o];
    }
    __syncthreads();
    float M[8];
    #pragma unroll
    for (int o = 0; o < 8; o++) M[o] = fmaxf(fmaxf(red[o], red[8 + o]), fmaxf(red[16 + o], red[24 + o]));
    float e0[8], e1[8], sm[8];
    #pragma unroll
    for (int o = 0; o < 8; o++) { e0[o] = expf(s0[o] - M[o]); e1[o] = expf(s1[o] - M[o]); sm[o] = e0[o] + e1[o]; }
    __syncthreads();
    for (int off = 1; off < 64; off <<= 1) {
        #pragma unroll
        for (int o = 0; o < 8; o++) sm[o] += __shfl_xor(sm[o], off);
    }
    if (lane == 0) {
        #pragma unroll
        for (int o = 0; o < 8; o++) red[wid * 8 + o] = sm[o];
    }
    __syncthreads();
    float a0[8], a1[8], st_s[8], st_q[8];
    #pragma unroll
    for (int o = 0; o < 8; o++) {
        float rden = 1.f / (red[o] + red[8 + o] + red[16 + o] + red[24 + o]);
        a0[o] = e0[o] * rden; a1[o] = e1[o] * rden;
        st_s[o] = a0[o] + a1[o];
        st_q[o] = a0[o] * a0[o] + a1[o] * a1[o];
    }
    size_t base = (size_t)i * 512;
    #pragma unroll
    for (int o = 0; o < 8; o++) {
        alpha[(size_t)o * LL + base + t] = a0[o];
        alpha[(size_t)o * LL + base + t + 256] = a1[o];
    }
    {   // pzb chunk 16 = alpha (ch 128..135), chunk 17 = zero pad
        uint4 p0, p1;
        p0.x = pack2(a0[0], a0[1]); p0.y = pack2(a0[2], a0[3]);
        p0.z = pack2(a0[4], a0[5]); p0.w = pack2(a0[6], a0[7]);
        p1.x = pack2(a1[0], a1[1]); p1.y = pack2(a1[2], a1[3]);
        p1.z = pack2(a1[4], a1[5]); p1.w = pack2(a1[6], a1[7]);
        unsigned short* pb = pzb + (size_t)i * PZROW + 16 * 4096;
        *(uint4*)(pb + (size_t)t * 8) = p0;
        *(uint4*)(pb + (size_t)(t + 256) * 8) = p1;
        uint4 zz = {0u, 0u, 0u, 0u};
        *(uint4*)(pb + 4096 + (size_t)t * 8) = zz;
        *(uint4*)(pb + 4096 + (size_t)(t + 256) * 8) = zz;
    }
    __syncthreads();
    for (int off = 1; off < 64; off <<= 1) {
        #pragma unroll
        for (int o = 0; o < 8; o++) { st_s[o] += __shfl_xor(st_s[o], off); st_q[o] += __shfl_xor(st_q[o], off); }
    }
    if (lane == 0) {
        #pragma unroll
        for (int o = 0; o < 8; o++) { red[wid * 8 + o] = st_s[o]; red[32 + wid * 8 + o] = st_q[o]; }
    }
    __syncthreads();
    if (t < 8) {
        float ts = red[t] + red[8 + t] + red[16 + t] + red[24 + t];
        float tq = red[32 + t] + red[40 + t] + red[48 + t] + red[56 + t];
        atomicAdd(&pz_acc[(128 + t) * 2], ts);
        atomicAdd(&pz_acc[(128 + t) * 2 + 1], tq);
    }
}

// ------------------------------------- features + MLP + residual layernorm -> x_out
__global__ __launch_bounds__(256) void feat_mlp_k(
        const float* __restrict__ alpha, const float* __restrict__ z,
        const float* __restrict__ vp, const float* __restrict__ pcb,
        const float* __restrict__ R, const float* __restrict__ tv,
        const float* __restrict__ W1, const float* __restrict__ b1,
        const float* __restrict__ ln1g, const float* __restrict__ ln1b,
        const float* __restrict__ W2, const float* __restrict__ b2,
        const float* __restrict__ lng, const float* __restrict__ lnb,
        const float* __restrict__ x, float* __restrict__ xout) {
    __shared__ float al[8 * 512];
    __shared__ float zl[64 * 128];
    __shared__ float feat[1536];
    __shared__ float h1[512];
    __shared__ float agg[216];
    __shared__ float Rt[12];
    __shared__ float redl[8];
    int i = blockIdx.x, t = threadIdx.x;
    for (int f = t; f < 4096; f += 256) al[f] = alpha[(size_t)(f >> 9) * LL + i * 512 + (f & 511)];
    if (t < 12) Rt[t] = (t < 9) ? R[i * 9 + t] : tv[i * 3 + t - 9];
    __syncthreads();
    if (t < 216) {
        float a = 0.f;
        if (t < 192) {
            int h = t / 24;
            const float* vptr = vp + t;
            const float* ar = al + h * 512;
            for (int j = 0; j < 512; j++) a += ar[j] * vptr[(size_t)j * 192];
        } else {
            int u = t - 192; int h = u / 3, cc = u % 3;
            const float* ar = al + h * 512;
            for (int j = 0; j < 512; j++) a += ar[j] * pcb[j * 3 + cc];
        }
        agg[t] = a;
    }
    float4 accp = {0.f, 0.f, 0.f, 0.f};
    int hh = t >> 5, p4 = t & 31;
    for (int jc = 0; jc < 8; jc++) {
        const float4* zsrc = (const float4*)(z + (size_t)(i * 512 + jc * 64) * 128);
        #pragma unroll
        for (int r = 0; r < 8; r++) ((float4*)zl)[r * 256 + t] = zsrc[r * 256 + t];
        __syncthreads();
        const float* ar = al + hh * 512 + jc * 64;
        const float4* zv = (const float4*)zl + p4;
        #pragma unroll 4
        for (int jl = 0; jl < 64; jl++) {
            float a = ar[jl];
            float4 v = zv[jl * 32];
            accp.x += a * v.x; accp.y += a * v.y; accp.z += a * v.z; accp.w += a * v.w;
        }
        __syncthreads();
    }
    *(float4*)&feat[hh * 128 + p4 * 4] = accp;
    __syncthreads();
    if (t < 64) {
        int h = t >> 3, v = t & 7;
        float d0 = agg[h * 24 + v * 3] - Rt[9];
        float d1 = agg[h * 24 + v * 3 + 1] - Rt[10];
        float d2 = agg[h * 24 + v * 3 + 2] - Rt[11];
        float f0 = Rt[0] * d0 + Rt[3] * d1 + Rt[6] * d2;
        float f1 = Rt[1] * d0 + Rt[4] * d1 + Rt[7] * d2;
        float f2 = Rt[2] * d0 + Rt[5] * d1 + Rt[8] * d2;
        float n = sqrtf(f0 * f0 + f1 * f1 + f2 * f2);
        float rn = 1.f / (n + 1e-6f);
        feat[1024 + h * 24 + v * 3] = f0;
        feat[1024 + h * 24 + v * 3 + 1] = f1;
        feat[1024 + h * 24 + v * 3 + 2] = f2;
        feat[1216 + h * 8 + v] = n;
        feat[1280 + h * 24 + v * 3] = f0 * rn;
        feat[1280 + h * 24 + v * 3 + 1] = f1 * rn;
        feat[1280 + h * 24 + v * 3 + 2] = f2 * rn;
    } else if (t < 72) {
        int h = t - 64;
        float d0 = agg[192 + h * 3] - Rt[9];
        float d1 = agg[192 + h * 3 + 1] - Rt[10];
        float d2 = agg[192 + h * 3 + 2] - Rt[11];
        float f0 = Rt[0] * d0 + Rt[3] * d1 + Rt[6] * d2;
        float f1 = Rt[1] * d0 + Rt[4] * d1 + Rt[7] * d2;
        float f2 = Rt[2] * d0 + Rt[5] * d1 + Rt[8] * d2;
        float n = sqrtf(f0 * f0 + f1 * f1 + f2 * f2);
        float rn = 1.f / (n + 1e-6f);
        feat[1472 + h * 3] = f0; feat[1472 + h * 3 + 1] = f1; feat[1472 + h * 3 + 2] = f2;
        feat[1496 + h] = n;
        feat[1504 + h * 3] = f0 * rn; feat[1504 + h * 3 + 1] = f1 * rn; feat[1504 + h * 3 + 2] = f2 * rn;
    }
    __syncthreads();
    float acc0 = b1[t], acc1 = b1[t + 256];
    const float4* f4 = (const float4*)feat;
    for (int f = 0; f < 1528; f += 4) {
        float4 fv = f4[f >> 2];
        const float* w = W1 + (size_t)f * 512 + t;
        acc0 += fv.x * w[0] + fv.y * w[512] + fv.z * w[1024] + fv.w * w[1536];
        const float* w2p = w + 256;
        acc1 += fv.x * w2p[0] + fv.y * w2p[512] + fv.z * w2p[1024] + fv.w * w2p[1536];
    }
    int lane = t & 63, wid = t >> 6;
    float s = acc0 + acc1, s2 = acc0 * acc0 + acc1 * acc1;
    for (int off = 1; off < 64; off <<= 1) { s += __shfl_xor(s, off); s2 += __shfl_xor(s2, off); }
    if (lane == 0) { redl[wid * 2] = s; redl[wid * 2 + 1] = s2; }
    __syncthreads();
    float S = redl[0] + redl[2] + redl[4] + redl[6];
    float S2 = redl[1] + redl[3] + redl[5] + redl[7];
    float mean = S / 512.f;
    float rstd = rsqrtf(fmaxf(S2 / 512.f - mean * mean, 0.f) + 1e-5f);
    float hv0 = (acc0 - mean) * rstd * ln1g[t] + ln1b[t];
    float hv1 = (acc1 - mean) * rstd * ln1g[t + 256] + ln1b[t + 256];
    hv0 = hv0 >= 0.f ? hv0 : 0.01f * hv0;
    hv1 = hv1 >= 0.f ? hv1 : 0.01f * hv1;
    h1[t] = hv0; h1[t + 256] = hv1;
    __syncthreads();
    float a2 = b2[t];
    const float4* h14 = (const float4*)h1;
    for (int k = 0; k < 512; k += 4) {
        float4 hv = h14[k >> 2];
        const float* w = W2 + (size_t)k * 256 + t;
        a2 += hv.x * w[0] + hv.y * w[256] + hv.z * w[512] + hv.w * w[768];
    }
    float xv = x[i * 256 + t] + a2;
    float ss_ = xv, sq_ = xv * xv;
    for (int off = 1; off < 64; off <<= 1) { ss_ += __shfl_xor(ss_, off); sq_ += __shfl_xor(sq_, off); }
    __syncthreads();
    if (lane == 0) { redl[wid * 2] = ss_; redl[wid * 2 + 1] = sq_; }
    __syncthreads();
    float Sx = redl[0] + redl[2] + redl[4] + redl[6];
    float Sx2 = redl[1] + redl[3] + redl[5] + redl[7];
    float mx = Sx / 256.f;
    float rsx = rsqrtf(fmaxf(Sx2 / 256.f - mx * mx, 0.f) + 1e-5f);
    xout[i * 256 + t] = (xv - mx) * rsx * lng[t] + lnb[t];
}

// ---------------- conv3(136->128) on precomputed raw-bf16 pzb, norm folded into wbT.
// T14 staging; COALESCED weight loads (wbT[tap][ksn][lhi][n][8k]);
// LDS-transposed coalesced float4 epilogue stores.
__global__ __launch_bounds__(256) void conv_mfma_k(
        const unsigned short* __restrict__ pzb, const unsigned short* __restrict__ wb,
        const float* __restrict__ kc, const float* __restrict__ cpb,
        float* __restrict__ pout) {
    __shared__ unsigned short abuf[2368 * 8];   // 18*130 = 2340 used 16B slots (>= 32KB f32 epilogue)
    __shared__ float csA[128];
    __shared__ float cs0[128];
    __shared__ float cs2[128];
    int t = threadIdx.x;
    int bid = blockIdx.x;
    int swz = (bid & 7) * 256 + (bid >> 3);     // bijective XCD swizzle (2048 % 8 == 0)
    int i = swz >> 2;
    int j0 = (swz & 3) * 128;
    if (t < 128) {
        int o = t;
        float a0 = 0.f, a1 = 0.f, a2 = 0.f;
        #pragma unroll
        for (int di = 0; di < 3; di++) {
            int grow = i - 1 + di;
            if (grow < 0 || grow > 511) continue;
            a0 += kc[o * 9 + di * 3];
            a1 += kc[o * 9 + di * 3 + 1];
            a2 += kc[o * 9 + di * 3 + 2];
        }
        cs0[o] = a0; cs2[o] = a2; csA[o] = cpb[o] + a0 + a1 + a2;
    }
    int w = t >> 6, lane = t & 63;
    int l31 = lane & 31, lhi = lane >> 5;
    int mt0 = (w & 1) * 64;      // wave's m base
    int nt0 = (w >> 1) * 64;     // wave's n base

    uint4 rg[10];
    #define STAGE_LOAD(DI) do {                                                \
        int grow_ = i - 1 + (DI);                                              \
        bool rowok_ = (grow_ >= 0 && grow_ < 512);                             \
        const unsigned short* rowp_ = pzb + (size_t)grow_ * PZROW;             \
        _Pragma("unroll")                                                      \
        for (int k = 0; k < 10; k++) {                                         \
            int f_ = t + k * 256;                                              \
            uint4 v_ = {0u, 0u, 0u, 0u};                                       \
            if (f_ < 2340) {                                                   \
                int c_ = f_ / 130, col_ = f_ - c_ * 130;                       \
                int gcol_ = j0 - 1 + col_;                                     \
                if (rowok_ && (unsigned)gcol_ < 512u)                          \
                    v_ = *(const uint4*)(rowp_ + c_ * 4096 + gcol_ * 8);       \
            }                                                                  \
            rg[k] = v_;                                                        \
        }                                                                      \
    } while (0)

    #define STAGE_WRITE() do {                                                 \
        _Pragma("unroll")                                                      \
        for (int k = 0; k < 10; k++) {                                         \
            int f_ = t + k * 256;                                              \
            if (f_ < 2340) *(uint4*)(abuf + f_ * 8) = rg[k];                   \
        }                                                                      \
    } while (0)

    f32x16 acc00 = {}, acc01 = {}, acc10 = {}, acc11 = {};

    STAGE_LOAD(0);
    STAGE_WRITE();
    __syncthreads();

    #pragma unroll
    for (int di = 0; di < 3; di++) {
        if (di < 2) STAGE_LOAD(di + 1);
        #pragma unroll
        for (int dj = 0; dj < 3; dj++) {
            int tap = di * 3 + dj;
            // wbT: lanes l31 read consecutive n -> contiguous 512B per half-wave
            const unsigned short* wt = wb + (size_t)(tap * 18 + lhi) * 1024 + (nt0 + l31) * 8;
            const unsigned short* ap0 = abuf + lhi * 1040 + (mt0 + l31 + dj) * 8;
            const unsigned short* ap1 = ap0 + 256;
            #pragma unroll
            for (int ksn = 0; ksn < 9; ksn++) {
                bf16x8 a0 = *(const bf16x8*)(ap0 + ksn * 2080);
                bf16x8 a1 = *(const bf16x8*)(ap1 + ksn * 2080);
                bf16x8 b0 = *(const bf16x8*)(wt + ksn * 2048);
                bf16x8 b1 = *(const bf16x8*)(wt + ksn * 2048 + 256);
                acc00 = __builtin_amdgcn_mfma_f32_32x32x16_bf16(a0, b0, acc00, 0, 0, 0);
                acc01 = __builtin_amdgcn_mfma_f32_32x32x16_bf16(a0, b1, acc01, 0, 0, 0);
                acc10 = __builtin_amdgcn_mfma_f32_32x32x16_bf16(a1, b0, acc10, 0, 0, 0);
                acc11 = __builtin_amdgcn_mfma_f32_32x32x16_bf16(a1, b1, acc11, 0, 0, 0);
            }
        }
        __syncthreads();
        if (di < 2) {
            STAGE_WRITE();
            __syncthreads();
        }
    }
    #undef STAGE_LOAD
    #undef STAGE_WRITE

    // ---- epilogue: bias + leaky -> LDS [64 rows][128 ch] -> coalesced float4 stores
    float* fb = (float*)abuf;
    #pragma unroll
    for (int mh = 0; mh < 2; mh++) {
        if ((w & 1) == mh) {
            #pragma unroll
            for (int mi = 0; mi < 2; mi++) {
                #pragma unroll
                for (int ni = 0; ni < 2; ni++) {
                    const f32x16* a = (mi == 0) ? (ni == 0 ? &acc00 : &acc01) : (ni == 0 ? &acc10 : &acc11);
                    int nb = nt0 + ni * 32 + l31;
                    float bA = csA[nb], b0_ = cs0[nb], b2_ = cs2[nb];
                    #pragma unroll
                    for (int r = 0; r < 16; r++) {
                        int ml = mi * 32 + 4 * lhi + (r & 3) + 8 * (r >> 2);
                        int j = j0 + mh * 64 + ml;
                        float bias = bA - (j == 0 ? b0_ : 0.f) - (j == 511 ? b2_ : 0.f);
                        float v = (*a)[r] + bias;
                        v = v >= 0.f ? v : 0.01f * v;
                        fb[ml * 128 + nb] = v;
                    }
                }
            }
        }
        __syncthreads();
        const float4* fb4 = (const float4*)fb;
        float4* gdst = (float4*)(pout + ((size_t)(i * 512 + j0 + mh * 64)) * 128);
        #pragma unroll
        for (int k = 0; k < 8; k++) {
            int f4i = k * 256 + t;
            gdst[f4i] = fb4[f4i];
        }
        __syncthreads();
    }
}

// ---------------------------------------------------------------- launcher
extern "C" void kernel_launch(void* const* d_in, const int* in_sizes, int n_in,
                              void* d_out, int out_size, void* d_ws, size_t ws_size,
                              hipStream_t stream) {
    (void)in_sizes; (void)n_in; (void)out_size; (void)ws_size;
    const float* R    = (const float*)d_in[0];
    const float* tv   = (const float*)d_in[1];
    const float* pcb  = (const float*)d_in[2];
    const float* x    = (const float*)d_in[3];
    const float* z    = (const float*)d_in[4];
    const float* wp2h = (const float*)d_in[5];
    const float* gamma= (const float*)d_in[6];
    const float* Wq   = (const float*)d_in[7];
    const float* Wk   = (const float*)d_in[8];
    const float* Wv   = (const float*)d_in[9];
    const float* W1   = (const float*)d_in[10];
    const float* b1   = (const float*)d_in[11];
    const float* ln1g = (const float*)d_in[12];
    const float* ln1b = (const float*)d_in[13];
    const float* W2   = (const float*)d_in[14];
    const float* b2   = (const float*)d_in[15];
    const float* caw  = (const float*)d_in[16];
    const float* cab  = (const float*)d_in[17];
    const float* lng  = (const float*)d_in[18];
    const float* lnb  = (const float*)d_in[19];
    const float* cpw  = (const float*)d_in[20];
    const float* cpb  = (const float*)d_in[21];

    float* ws = (float*)d_ws;
    float* qs     = ws;                 // 512*192
    float* ksv    = qs + 98304;
    float* vp     = ksv + 98304;
    float* q2     = vp + 98304;         // pad 4096
    float* k2     = q2 + 4096;
    float* lg_acc = k2 + 4096;          // 32
    float* lg_mr  = lg_acc + 32;        // 32
    float* pz_acc = lg_mr + 32;         // 272
    float* pz_mr  = pz_acc + 272;       // 272
    float* kc     = pz_mr + 272;        // 1152
    unsigned short* wbq = (unsigned short*)(kc + 1152);     // 128*1296 bf16 = 82944 floats
    float* lg     = kc + 1152 + 82944;                      // 16*LL
    float* alpha  = lg + 16 * LL;                           // 8*LL
    unsigned short* pzb = (unsigned short*)(alpha + 8 * LL);// 512*73728 bf16

    float* xout = (float*)d_out;
    float* pout = xout + 131072;

    hipLaunchKernelGGL(zero_stats_k, dim3(1), dim3(512), 0, stream, lg_acc, pz_acc);
    hipLaunchKernelGGL(qkv_k, dim3(512), dim3(256), 0, stream, x, Wq, Wk, Wv, R, tv, qs, ksv, vp, q2, k2);
    hipLaunchKernelGGL(zstats_pzb_k, dim3(2048), dim3(256), 0, stream, (const float4*)z, pz_acc, pzb);
    hipLaunchKernelGGL(lg_k, dim3(512), dim3(256), 0, stream, z, wp2h, gamma, qs, ksv, q2, k2, lg, lg_acc);
    hipLaunchKernelGGL(finalize_k, dim3(1), dim3(64), 0, stream, lg_acc, lg_mr, 16, 262144.f);
    hipLaunchKernelGGL(ca_softmax_k, dim3(512), dim3(256), 0, stream, lg, lg_mr, caw, cab, alpha, pz_acc, pzb);
    hipLaunchKernelGGL(finalize_k, dim3(1), dim3(192), 0, stream, pz_acc, pz_mr, 136, 262144.f);
    hipLaunchKernelGGL(wb_prep_k, dim3(648), dim3(256), 0, stream, cpw, pz_mr, wbq);
    hipLaunchKernelGGL(kc_prep_k, dim3(9), dim3(128), 0, stream, cpw, pz_mr, kc);
    hipLaunchKernelGGL(feat_mlp_k, dim3(512), dim3(256), 0, stream,
                       alpha, z, vp, pcb, R, tv, W1, b1, ln1g, ln1b, W2, b2, lng, lnb, x, xout);
    hipLaunchKernelGGL(conv_mfma_k, dim3(2048), dim3(256), 0, stream, pzb, wbq, kc, cpb, pout);
}

// Round 6
// 753.226 us; speedup vs baseline: 1.0991x; 1.0272x over previous
//
#include <hip/hip_runtime.h>
#include <hip/hip_bf16.h>
#include <math.h>

#define Lr 512
#define LL (512*512)
#define PZROW 73728   // shorts per pzb row: 18 chunks * 512 cols * 8ch

typedef __bf16 bf16x8 __attribute__((ext_vector_type(8)));
typedef float f32x16 __attribute__((ext_vector_type(16)));

static __device__ __forceinline__ unsigned short f2bf(float f) {
    union { float f; unsigned u; } a; a.f = f;
    unsigned r = a.u + 0x7fff + ((a.u >> 16) & 1);
    return (unsigned short)(r >> 16);
}

static __device__ __forceinline__ unsigned pack2(float lo, float hi) {
    return (unsigned)f2bf(lo) | ((unsigned)f2bf(hi) << 16);
}

static __device__ __forceinline__ float bflo(unsigned u) {
    union { unsigned u; float f; } c; c.u = u << 16; return c.f;
}
static __device__ __forceinline__ float bfhi(unsigned u) {
    union { unsigned u; float f; } c; c.u = u & 0xffff0000u; return c.f;
}

// ---------------------------------------------------------------- zero stats
__global__ __launch_bounds__(512) void zero_stats_k(float* lg_acc, float* pz_acc) {
    int t = threadIdx.x;
    if (t < 32) lg_acc[t] = 0.f;
    if (t < 272) pz_acc[t] = 0.f;
}

// ------ cp_w * rs -> bf16 wbT[tap][ksn][lhi][n][8k]  (norm folded, COALESCED)
__global__ __launch_bounds__(256) void wb_prep_k(const float* __restrict__ cpw,
        const float* __restrict__ pzmr, unsigned short* __restrict__ wb) {
    int idx = blockIdx.x * 256 + threadIdx.x;
    if (idx >= 128 * 1296) return;
    int j = idx & 7;
    int n = (idx >> 3) & 127;
    int rest = idx >> 10;
    int lhi = rest & 1;
    int ksn = (rest >> 1) % 9;
    int tap = rest / 18;
    int c = ksn * 16 + lhi * 8 + j;
    float v = (c < 136) ? cpw[(n * 136 + c) * 9 + tap] * pzmr[c * 2 + 1] : 0.f;
    wb[idx] = f2bf(v);
}

// ------ W1 -> bf16 w1t[k8][col][8k]: w1t[(k8*512+t)*8+s] = bf16(W1[(k8*8+s)*512+t])
__global__ __launch_bounds__(256) void w1t_prep_k(const float* __restrict__ W1,
        unsigned short* __restrict__ w1t) {
    int idx = blockIdx.x * 256 + threadIdx.x;   // 512*1528 = 782336
    if (idx >= 782336) return;
    int s = idx & 7;
    int t = (idx >> 3) & 511;
    int k8 = idx >> 12;
    w1t[idx] = f2bf(W1[(size_t)(k8 * 8 + s) * 512 + t]);
}

// ---------------- kc[o][tap] = -sum_c w[o,c,tap]*rs_c*m_c  (mean correction)
__global__ __launch_bounds__(128) void kc_prep_k(const float* __restrict__ cpw,
        const float* __restrict__ pzmr, float* __restrict__ kc) {
    int idx = blockIdx.x * 128 + threadIdx.x;
    if (idx >= 1152) return;
    int o = idx / 9, tap = idx % 9;
    float s = 0.f;
    for (int c = 0; c < 136; c++)
        s += cpw[(o * 136 + c) * 9 + tap] * pzmr[c * 2 + 1] * pzmr[c * 2];
    kc[idx] = -s;
}

// ---------------------------------------------------------------- qkv + l2g
__device__ __forceinline__ const float* qkv_colptr(const float* Wq, const float* Wk, const float* Wv, int c) {
    return c < 192 ? (Wq + c) : (c < 384 ? (Wk + c - 192) : (Wv + c - 384));
}

__global__ __launch_bounds__(256) void qkv_k(const float* __restrict__ x,
        const float* __restrict__ Wq, const float* __restrict__ Wk, const float* __restrict__ Wv,
        const float* __restrict__ R, const float* __restrict__ tv,
        float* __restrict__ qs, float* __restrict__ ks, float* __restrict__ vp,
        float* __restrict__ q2, float* __restrict__ k2) {
    __shared__ float xrow[256];
    __shared__ float praw[576];
    __shared__ float tr[576];
    __shared__ float Rt[12];
    int i = blockIdx.x, t = threadIdx.x;
    xrow[t] = x[i * 256 + t];
    if (t < 12) Rt[t] = (t < 9) ? R[i * 9 + t] : tv[i * 3 + t - 9];
    __syncthreads();
    const float* p0 = qkv_colptr(Wq, Wk, Wv, t);
    const float* p1 = qkv_colptr(Wq, Wk, Wv, t + 256);
    const float* p2 = qkv_colptr(Wq, Wk, Wv, t < 64 ? t + 512 : 575);
    float a0 = 0.f, a1 = 0.f, a2 = 0.f;
    for (int f = 0; f < 256; f++) {
        float xv = xrow[f];
        a0 += xv * p0[f * 192];
        a1 += xv * p1[f * 192];
        a2 += xv * p2[f * 192];
    }
    praw[t] = a0; praw[t + 256] = a1;
    if (t < 64) praw[t + 512] = a2;
    __syncthreads();
    if (t < 192) {
        int seg = t / 64, pt = t % 64;
        float b0 = praw[seg * 192 + pt * 3], b1_ = praw[seg * 192 + pt * 3 + 1], b2_ = praw[seg * 192 + pt * 3 + 2];
        #pragma unroll
        for (int r = 0; r < 3; r++)
            tr[seg * 192 + pt * 3 + r] = Rt[r * 3] * b0 + Rt[r * 3 + 1] * b1_ + Rt[r * 3 + 2] * b2_ + Rt[9 + r];
    }
    __syncthreads();
    if (t < 8) {
        float s = 0.f;
        #pragma unroll
        for (int d = 0; d < 24; d++) { float v = tr[t * 24 + d]; s += v * v; }
        q2[i * 8 + t] = s;
    } else if (t < 16) {
        int h = t - 8; float s = 0.f;
        #pragma unroll
        for (int d = 0; d < 24; d++) { float v = tr[192 + h * 24 + d]; s += v * v; }
        k2[i * 8 + h] = s;
    }
    for (int f = t; f < 576; f += 256) {
        float v = tr[f];
        if (f < 192) qs[i * 192 + f] = v;
        else if (f < 384) ks[i * 192 + f - 192] = v;
        else vp[i * 192 + f - 384] = v;
    }
}

// -------------------- z channel stats + raw-bf16 pzb z-part (chunks 0..15)
__global__ __launch_bounds__(256) void zstats_pzb_k(const float4* __restrict__ z4,
        float* pz_acc, unsigned short* __restrict__ pzb) {
    __shared__ float acc[256];   // 128 ch x {sum, sumsq}
    int t = threadIdx.x;
    acc[t] = 0.f;
    __syncthreads();
    int chunk = t & 15, pl = t >> 4;
    int p0 = blockIdx.x * 128;
    float s[8], s2[8];
    #pragma unroll
    for (int u = 0; u < 8; u++) { s[u] = 0.f; s2[u] = 0.f; }
    #pragma unroll
    for (int k = 0; k < 8; k++) {
        int pos = p0 + k * 16 + pl;
        const float4* src = z4 + (size_t)pos * 32 + chunk * 2;
        float4 v0 = src[0], v1 = src[1];
        float vv[8] = {v0.x, v0.y, v0.z, v0.w, v1.x, v1.y, v1.z, v1.w};
        #pragma unroll
        for (int u = 0; u < 8; u++) { s[u] += vv[u]; s2[u] += vv[u] * vv[u]; }
        uint4 q;
        q.x = pack2(vv[0], vv[1]); q.y = pack2(vv[2], vv[3]);
        q.z = pack2(vv[4], vv[5]); q.w = pack2(vv[6], vv[7]);
        int row = pos >> 9, col = pos & 511;
        *(uint4*)(pzb + ((size_t)row * 18 + chunk) * 4096 + col * 8) = q;
    }
    #pragma unroll
    for (int u = 0; u < 8; u++) {
        atomicAdd(&acc[(chunk * 8 + u) * 2], s[u]);
        atomicAdd(&acc[(chunk * 8 + u) * 2 + 1], s2[u]);
    }
    __syncthreads();
    if (t < 128) {
        atomicAdd(&pz_acc[t * 2], acc[t * 2]);
        atomicAdd(&pz_acc[t * 2 + 1], acc[t * 2 + 1]);
    }
}

// ------------------------------------------- logits_pair + logits_spatial (lg) + stats
__global__ __launch_bounds__(256) void lg_k(const float* __restrict__ z,
        const float* __restrict__ Wp2h, const float* __restrict__ gamma,
        const float* __restrict__ qs, const float* __restrict__ ks,
        const float* __restrict__ q2, const float* __restrict__ k2,
        float* __restrict__ lg, float* lg_acc) {
    __shared__ float zl[32 * 132];
    __shared__ float wh[8 * 132];
    __shared__ float qrow[192];
    __shared__ float q2row[8];
    __shared__ float sacc[32];
    int i = blockIdx.x, t = threadIdx.x;
    for (int f = t; f < 1024; f += 256) { int h = f >> 7, p = f & 127; wh[h * 132 + p] = Wp2h[p * 8 + h]; }
    if (t < 192) qrow[t] = qs[i * 192 + t];
    if (t < 8) q2row[t] = q2[i * 8 + t];
    if (t < 32) sacc[t] = 0.f;
    int jl = t >> 3, h = t & 7;
    float gsc = -gamma[h] * 0.08333333333333333f;
    float sp = 0.f, sp2 = 0.f, ss = 0.f, ss2 = 0.f;
    __syncthreads();
    for (int jt = 0; jt < 16; jt++) {
        int j0 = jt * 32;
        const float4* zsrc = (const float4*)(z + (size_t)(i * 512 + j0) * 128);
        #pragma unroll
        for (int r = 0; r < 4; r++) {
            int idx4 = r * 256 + t;
            int zjl = idx4 >> 5, p4 = idx4 & 31;
            *(float4*)&zl[zjl * 132 + p4 * 4] = zsrc[idx4];
        }
        __syncthreads();
        int j = j0 + jl;
        float accp = 0.f;
        const float4* za = (const float4*)&zl[jl * 132];
        const float4* wa = (const float4*)&wh[h * 132];
        #pragma unroll
        for (int p4 = 0; p4 < 32; p4++) {
            float4 a = za[p4], b = wa[p4];
            accp += a.x * b.x + a.y * b.y + a.z * b.z + a.w * b.w;
        }
        const float4* kp = (const float4*)(ks + (size_t)j * 192 + h * 24);
        const float4* qp = (const float4*)&qrow[h * 24];
        float dqk = 0.f;
        #pragma unroll
        for (int d4 = 0; d4 < 6; d4++) {
            float4 a = qp[d4], b = kp[d4];
            dqk += a.x * b.x + a.y * b.y + a.z * b.z + a.w * b.w;
        }
        float ssd = q2row[h] + k2[j * 8 + h] - 2.f * dqk;
        float lgs = ssd * gsc;
        lg[(size_t)h * LL + i * 512 + j] = accp;
        lg[(size_t)(8 + h) * LL + i * 512 + j] = lgs;
        sp += accp; sp2 += accp * accp; ss += lgs; ss2 += lgs * lgs;
        __syncthreads();
    }
    atomicAdd(&sacc[h * 2], sp);        atomicAdd(&sacc[h * 2 + 1], sp2);
    atomicAdd(&sacc[16 + h * 2], ss);   atomicAdd(&sacc[16 + h * 2 + 1], ss2);
    __syncthreads();
    if (t < 16) {
        atomicAdd(&lg_acc[t * 2], sacc[t * 2]);
        atomicAdd(&lg_acc[t * 2 + 1], sacc[t * 2 + 1]);
    }
}

// ---------------------------------------------------------------- stats -> mean,rstd
__global__ void finalize_k(const float* __restrict__ acc, float* __restrict__ mr, int nch, float npix) {
    int t = threadIdx.x;
    if (t < nch) {
        float m = acc[t * 2] / npix;
        float v = acc[t * 2 + 1] / npix - m * m;
        mr[t * 2] = m;
        mr[t * 2 + 1] = rsqrtf(fmaxf(v, 0.f) + 1e-5f);
    }
}

// ----------------------------------- inorm(lg) -> conv3(16->8) -> leaky -> softmax(j)
// + emit pzb chunks 16 (alpha bf16) and 17 (zero pad)
__global__ __launch_bounds__(256) void ca_softmax_k(const float* __restrict__ lg,
        const float* __restrict__ lgmr, const float* __restrict__ caw, const float* __restrict__ cab,
        float* __restrict__ alpha, float* pz_acc, unsigned short* __restrict__ pzb) {
    __shared__ float wl[1152];
    __shared__ float mr[32];
    __shared__ float cb[8];
    __shared__ float red[64];
    int i = blockIdx.x, t = threadIdx.x;
    for (int f = t; f < 1152; f += 256) {
        int o = f & 7, k = f >> 3; int c = k / 9, r = k % 9;
        wl[f] = caw[(o * 16 + c) * 9 + r];
    }
    if (t < 32) mr[t] = lgmr[t];
    if (t < 8) cb[t] = cab[t];
    __syncthreads();
    float acc0[8], acc1[8];
    #pragma unroll
    for (int o = 0; o < 8; o++) { acc0[o] = 0.f; acc1[o] = 0.f; }
    int j0 = t, j1 = t + 256;
    const float4* w4 = (const float4*)wl;
    for (int c = 0; c < 16; c++) {
        float m = mr[c * 2], rs = mr[c * 2 + 1];
        const float* lgc = lg + (size_t)c * LL;
        #pragma unroll
        for (int di = 0; di < 3; di++) {
            int row = i - 1 + di;
            if (row < 0 || row >= 512) continue;
            const float* lr = lgc + (size_t)row * 512;
            float v0[3], v1[3];
            v0[0] = (j0 > 0) ? (lr[j0 - 1] - m) * rs : 0.f;
            v0[1] = (lr[j0] - m) * rs;
            v0[2] = (lr[j0 + 1] - m) * rs;
            v1[0] = (lr[j1 - 1] - m) * rs;
            v1[1] = (lr[j1] - m) * rs;
            v1[2] = (j1 < 511) ? (lr[j1 + 1] - m) * rs : 0.f;
            int wb = (c * 9 + di * 3) * 2;
            #pragma unroll
            for (int dj = 0; dj < 3; dj++) {
                float4 wa = w4[wb + dj * 2], wbv = w4[wb + dj * 2 + 1];
                acc0[0] += wa.x * v0[dj]; acc0[1] += wa.y * v0[dj]; acc0[2] += wa.z * v0[dj]; acc0[3] += wa.w * v0[dj];
                acc0[4] += wbv.x * v0[dj]; acc0[5] += wbv.y * v0[dj]; acc0[6] += wbv.z * v0[dj]; acc0[7] += wbv.w * v0[dj];
                acc1[0] += wa.x * v1[dj]; acc1[1] += wa.y * v1[dj]; acc1[2] += wa.z * v1[dj]; acc1[3] += wa.w * v1[dj];
                acc1[4] += wbv.x * v1[dj]; acc1[5] += wbv.y * v1[dj]; acc1[6] += wbv.z * v1[dj]; acc1[7] += wbv.w * v1[dj];
            }
        }
    }
    float s0[8], s1[8];
    #pragma unroll
    for (int o = 0; o < 8; o++) {
        float v = acc0[o] + cb[o]; s0[o] = v >= 0.f ? v : 0.01f * v;
        float w = acc1[o] + cb[o]; s1[o] = w >= 0.f ? w : 0.01f * w;
    }
    int lane = t & 63, wid = t >> 6;
    float mx[8];
    #pragma unroll
    for (int o = 0; o < 8; o++) mx[o] = fmaxf(s0[o], s1[o]);
    for (int off = 1; off < 64; off <<= 1) {
        #pragma unroll
        for (int o = 0; o < 8; o++) mx[o] = fmaxf(mx[o], __shfl_xor(mx[o], off));
    }
    if (lane == 0) {
        #pragma unroll
        for (int o = 0; o < 8; o++) red[wid * 8 + o] = mx[o];
    }
    __syncthreads();
    float M[8];
    #pragma unroll
    for (int o = 0; o < 8; o++) M[o] = fmaxf(fmaxf(red[o], red[8 + o]), fmaxf(red[16 + o], red[24 + o]));
    float e0[8], e1[8], sm[8];
    #pragma unroll
    for (int o = 0; o < 8; o++) { e0[o] = expf(s0[o] - M[o]); e1[o] = expf(s1[o] - M[o]); sm[o] = e0[o] + e1[o]; }
    __syncthreads();
    for (int off = 1; off < 64; off <<= 1) {
        #pragma unroll
        for (int o = 0; o < 8; o++) sm[o] += __shfl_xor(sm[o], off);
    }
    if (lane == 0) {
        #pragma unroll
        for (int o = 0; o < 8; o++) red[wid * 8 + o] = sm[o];
    }
    __syncthreads();
    float a0[8], a1[8], st_s[8], st_q[8];
    #pragma unroll
    for (int o = 0; o < 8; o++) {
        float rden = 1.f / (red[o] + red[8 + o] + red[16 + o] + red[24 + o]);
        a0[o] = e0[o] * rden; a1[o] = e1[o] * rden;
        st_s[o] = a0[o] + a1[o];
        st_q[o] = a0[o] * a0[o] + a1[o] * a1[o];
    }
    size_t base = (size_t)i * 512;
    #pragma unroll
    for (int o = 0; o < 8; o++) {
        alpha[(size_t)o * LL + base + t] = a0[o];
        alpha[(size_t)o * LL + base + t + 256] = a1[o];
    }
    {   // pzb chunk 16 = alpha (ch 128..135), chunk 17 = zero pad
        uint4 p0, p1;
        p0.x = pack2(a0[0], a0[1]); p0.y = pack2(a0[2], a0[3]);
        p0.z = pack2(a0[4], a0[5]); p0.w = pack2(a0[6], a0[7]);
        p1.x = pack2(a1[0], a1[1]); p1.y = pack2(a1[2], a1[3]);
        p1.z = pack2(a1[4], a1[5]); p1.w = pack2(a1[6], a1[7]);
        unsigned short* pb = pzb + (size_t)i * PZROW + 16 * 4096;
        *(uint4*)(pb + (size_t)t * 8) = p0;
        *(uint4*)(pb + (size_t)(t + 256) * 8) = p1;
        uint4 zz = {0u, 0u, 0u, 0u};
        *(uint4*)(pb + 4096 + (size_t)t * 8) = zz;
        *(uint4*)(pb + 4096 + (size_t)(t + 256) * 8) = zz;
    }
    __syncthreads();
    for (int off = 1; off < 64; off <<= 1) {
        #pragma unroll
        for (int o = 0; o < 8; o++) { st_s[o] += __shfl_xor(st_s[o], off); st_q[o] += __shfl_xor(st_q[o], off); }
    }
    if (lane == 0) {
        #pragma unroll
        for (int o = 0; o < 8; o++) { red[wid * 8 + o] = st_s[o]; red[32 + wid * 8 + o] = st_q[o]; }
    }
    __syncthreads();
    if (t < 8) {
        float ts = red[t] + red[8 + t] + red[16 + t] + red[24 + t];
        float tq = red[32 + t] + red[40 + t] + red[48 + t] + red[56 + t];
        atomicAdd(&pz_acc[(128 + t) * 2], ts);
        atomicAdd(&pz_acc[(128 + t) * 2 + 1], tq);
    }
}

// --------- features + MLP + residual layernorm -> x_out  (2 rows/block, 512 thr)
// W1 in bf16 coalesced layout w1t[k8][col][8k]; W1 stream halved + halved again by bf16.
__global__ __launch_bounds__(512) void feat_mlp2_k(
        const float* __restrict__ alpha, const float* __restrict__ z,
        const float* __restrict__ vp, const float* __restrict__ pcb,
        const float* __restrict__ R, const float* __restrict__ tv,
        const unsigned short* __restrict__ w1t, const float* __restrict__ b1,
        const float* __restrict__ ln1g, const float* __restrict__ ln1b,
        const float* __restrict__ W2, const float* __restrict__ b2,
        const float* __restrict__ lng, const float* __restrict__ lnb,
        const float* __restrict__ x, float* __restrict__ xout) {
    __shared__ float al2[2][4096];     // [r][o*512+j]  32 KB
    __shared__ float feat2[2][1536];   // 12 KB
    __shared__ float h1l[2][512];      // 4 KB
    __shared__ float agg2[2][216];
    __shared__ float Rt2[2][12];
    __shared__ float redl[32];
    int t = threadIdx.x;
    int i0 = blockIdx.x * 2;
    // alpha -> LDS (both rows)
    for (int f = t; f < 2048; f += 512) {
        int r = f >> 10, q = f & 1023;
        ((float4*)al2[r])[q] =
            ((const float4*)(alpha + (size_t)(q >> 7) * LL + (size_t)(i0 + r) * 512))[q & 127];
    }
    if (t < 24) { int r = t / 12, u = t % 12; Rt2[r][u] = (u < 9) ? R[(i0 + r) * 9 + u] : tv[(i0 + r) * 3 + u - 9]; }
    __syncthreads();
    // z·alpha: thread owns (r, hh, p4); direct z reads (L1-served)
    {
        int r = t >> 8, hh = (t >> 5) & 7, p4 = t & 31;
        const float4* zr4 = (const float4*)z + (size_t)(i0 + r) * 512 * 32 + p4;
        const float* ar = al2[r] + hh * 512;
        float4 accp = {0.f, 0.f, 0.f, 0.f};
        #pragma unroll 8
        for (int j = 0; j < 512; j++) {
            float a = ar[j];
            float4 v = zr4[(size_t)j * 32];
            accp.x += a * v.x; accp.y += a * v.y; accp.z += a * v.z; accp.w += a * v.w;
        }
        *(float4*)&feat2[r][hh * 128 + p4 * 4] = accp;
    }
    // agg: 432 threads, both rows
    if (t < 432) {
        int rr = t / 216, u = t - (t / 216) * 216;
        const float* ar;
        float acc = 0.f;
        if (u < 192) {
            int h = u / 24;
            ar = al2[rr] + h * 512;
            #pragma unroll 4
            for (int j = 0; j < 512; j++) acc += ar[j] * vp[(size_t)j * 192 + u];
        } else {
            int v_ = u - 192; int h = v_ / 3, cc = v_ % 3;
            ar = al2[rr] + h * 512;
            #pragma unroll 4
            for (int j = 0; j < 512; j++) acc += ar[j] * pcb[j * 3 + cc];
        }
        agg2[rr][u] = acc;
    }
    __syncthreads();
    // geometric transforms (both rows)
    if (t < 128) {
        int rr = t >> 6, idx = t & 63;
        int h = idx >> 3, vv = idx & 7;
        const float* Rt = Rt2[rr];
        float* feat = feat2[rr];
        const float* agg = agg2[rr];
        float d0 = agg[h * 24 + vv * 3] - Rt[9];
        float d1 = agg[h * 24 + vv * 3 + 1] - Rt[10];
        float d2 = agg[h * 24 + vv * 3 + 2] - Rt[11];
        float f0 = Rt[0] * d0 + Rt[3] * d1 + Rt[6] * d2;
        float f1 = Rt[1] * d0 + Rt[4] * d1 + Rt[7] * d2;
        float f2 = Rt[2] * d0 + Rt[5] * d1 + Rt[8] * d2;
        float n = sqrtf(f0 * f0 + f1 * f1 + f2 * f2);
        float rn = 1.f / (n + 1e-6f);
        feat[1024 + h * 24 + vv * 3] = f0;
        feat[1024 + h * 24 + vv * 3 + 1] = f1;
        feat[1024 + h * 24 + vv * 3 + 2] = f2;
        feat[1216 + h * 8 + vv] = n;
        feat[1280 + h * 24 + vv * 3] = f0 * rn;
        feat[1280 + h * 24 + vv * 3 + 1] = f1 * rn;
        feat[1280 + h * 24 + vv * 3 + 2] = f2 * rn;
    } else if (t < 144) {
        int u = t - 128; int rr = u >> 3, h = u & 7;
        const float* Rt = Rt2[rr];
        float* feat = feat2[rr];
        const float* agg = agg2[rr];
        float d0 = agg[192 + h * 3] - Rt[9];
        float d1 = agg[192 + h * 3 + 1] - Rt[10];
        float d2 = agg[192 + h * 3 + 2] - Rt[11];
        float f0 = Rt[0] * d0 + Rt[3] * d1 + Rt[6] * d2;
        float f1 = Rt[1] * d0 + Rt[4] * d1 + Rt[7] * d2;
        float f2 = Rt[2] * d0 + Rt[5] * d1 + Rt[8] * d2;
        float n = sqrtf(f0 * f0 + f1 * f1 + f2 * f2);
        float rn = 1.f / (n + 1e-6f);
        feat[1472 + h * 3] = f0; feat[1472 + h * 3 + 1] = f1; feat[1472 + h * 3 + 2] = f2;
        feat[1496 + h] = n;
        feat[1504 + h * 3] = f0 * rn; feat[1504 + h * 3 + 1] = f1 * rn; feat[1504 + h * 3 + 2] = f2 * rn;
    }
    __syncthreads();
    // W1 GEMV: thread owns out-col t for BOTH rows; w1t coalesced uint4 (8 bf16 k)
    float acc0 = b1[t], acc1 = acc0;
    {
        const float4* f40 = (const float4*)feat2[0];
        const float4* f41 = (const float4*)feat2[1];
        const uint4* wp = (const uint4*)(w1t + (size_t)t * 8);
        #pragma unroll 4
        for (int k8 = 0; k8 < 191; k8++) {
            uint4 wv = wp[(size_t)k8 * 512];
            float w0 = bflo(wv.x), w1 = bfhi(wv.x);
            float w2 = bflo(wv.y), w3 = bfhi(wv.y);
            float w4 = bflo(wv.z), w5 = bfhi(wv.z);
            float w6 = bflo(wv.w), w7 = bfhi(wv.w);
            float4 fa0 = f40[k8 * 2], fb0 = f40[k8 * 2 + 1];
            float4 fa1 = f41[k8 * 2], fb1 = f41[k8 * 2 + 1];
            acc0 += fa0.x * w0 + fa0.y * w1 + fa0.z * w2 + fa0.w * w3
                  + fb0.x * w4 + fb0.y * w5 + fb0.z * w6 + fb0.w * w7;
            acc1 += fa1.x * w0 + fa1.y * w1 + fa1.z * w2 + fa1.w * w3
                  + fb1.x * w4 + fb1.y * w5 + fb1.z * w6 + fb1.w * w7;
        }
    }
    int lane = t & 63, wid = t >> 6;
    // LN1 over 512 outs, per row
    {
        float s0 = acc0, q0 = acc0 * acc0, s1 = acc1, q1 = acc1 * acc1;
        for (int off = 1; off < 64; off <<= 1) {
            s0 += __shfl_xor(s0, off); q0 += __shfl_xor(q0, off);
            s1 += __shfl_xor(s1, off); q1 += __shfl_xor(q1, off);
        }
        if (lane == 0) { redl[wid * 4] = s0; redl[wid * 4 + 1] = q0; redl[wid * 4 + 2] = s1; redl[wid * 4 + 3] = q1; }
        __syncthreads();
        float S0 = 0.f, Q0 = 0.f, S1 = 0.f, Q1 = 0.f;
        #pragma unroll
        for (int w_ = 0; w_ < 8; w_++) { S0 += redl[w_ * 4]; Q0 += redl[w_ * 4 + 1]; S1 += redl[w_ * 4 + 2]; Q1 += redl[w_ * 4 + 3]; }
        float m0 = S0 / 512.f, r0 = rsqrtf(fmaxf(Q0 / 512.f - m0 * m0, 0.f) + 1e-5f);
        float m1 = S1 / 512.f, r1 = rsqrtf(fmaxf(Q1 / 512.f - m1 * m1, 0.f) + 1e-5f);
        float g = ln1g[t], bb = ln1b[t];
        float h0 = (acc0 - m0) * r0 * g + bb; h0 = h0 >= 0.f ? h0 : 0.01f * h0;
        float h1_ = (acc1 - m1) * r1 * g + bb; h1_ = h1_ >= 0.f ? h1_ : 0.01f * h1_;
        h1l[0][t] = h0; h1l[1][t] = h1_;
    }
    __syncthreads();
    // W2: thread owns (r2 = t>>8, c = t&255)
    int r2 = t >> 8, c = t & 255;
    float a2 = b2[c];
    {
        const float4* h4 = (const float4*)h1l[r2];
        #pragma unroll 4
        for (int k = 0; k < 512; k += 4) {
            float4 hv = h4[k >> 2];
            const float* w = W2 + (size_t)k * 256 + c;
            a2 += hv.x * w[0] + hv.y * w[256] + hv.z * w[512] + hv.w * w[768];
        }
    }
    float xv = x[(size_t)(i0 + r2) * 256 + c] + a2;
    {
        float ss = xv, qq = xv * xv;
        for (int off = 1; off < 64; off <<= 1) { ss += __shfl_xor(ss, off); qq += __shfl_xor(qq, off); }
        __syncthreads();   // all LN1-redl reads done
        if (lane == 0) { redl[wid * 2] = ss; redl[wid * 2 + 1] = qq; }
        __syncthreads();
        float Sx = redl[r2 * 8] + redl[r2 * 8 + 2] + redl[r2 * 8 + 4] + redl[r2 * 8 + 6];
        float Qx = redl[r2 * 8 + 1] + redl[r2 * 8 + 3] + redl[r2 * 8 + 5] + redl[r2 * 8 + 7];
        float mx = Sx / 256.f, rsx = rsqrtf(fmaxf(Qx / 256.f - mx * mx, 0.f) + 1e-5f);
        xout[(size_t)(i0 + r2) * 256 + c] = (xv - mx) * rsx * lng[c] + lnb[c];
    }
}

// ---------------- conv3(136->128) on precomputed raw-bf16 pzb, norm folded into wbT.
__global__ __launch_bounds__(256) void conv_mfma_k(
        const unsigned short* __restrict__ pzb, const unsigned short* __restrict__ wb,
        const float* __restrict__ kc, const float* __restrict__ cpb,
        float* __restrict__ pout) {
    __shared__ unsigned short abuf[2368 * 8];
    __shared__ float csA[128];
    __shared__ float cs0[128];
    __shared__ float cs2[128];
    int t = threadIdx.x;
    int bid = blockIdx.x;
    int swz = (bid & 7) * 256 + (bid >> 3);
    int i = swz >> 2;
    int j0 = (swz & 3) * 128;
    if (t < 128) {
        int o = t;
        float a0 = 0.f, a1 = 0.f, a2 = 0.f;
        #pragma unroll
        for (int di = 0; di < 3; di++) {
            int grow = i - 1 + di;
            if (grow < 0 || grow > 511) continue;
            a0 += kc[o * 9 + di * 3];
            a1 += kc[o * 9 + di * 3 + 1];
            a2 += kc[o * 9 + di * 3 + 2];
        }
        cs0[o] = a0; cs2[o] = a2; csA[o] = cpb[o] + a0 + a1 + a2;
    }
    int w = t >> 6, lane = t & 63;
    int l31 = lane & 31, lhi = lane >> 5;
    int mt0 = (w & 1) * 64;
    int nt0 = (w >> 1) * 64;

    uint4 rg[10];
    #define STAGE_LOAD(DI) do {                                                \
        int grow_ = i - 1 + (DI);                                              \
        bool rowok_ = (grow_ >= 0 && grow_ < 512);                             \
        const unsigned short* rowp_ = pzb + (size_t)grow_ * PZROW;             \
        _Pragma("unroll")                                                      \
        for (int k = 0; k < 10; k++) {                                         \
            int f_ = t + k * 256;                                              \
            uint4 v_ = {0u, 0u, 0u, 0u};                                       \
            if (f_ < 2340) {                                                   \
                int c_ = f_ / 130, col_ = f_ - c_ * 130;                       \
                int gcol_ = j0 - 1 + col_;                                     \
                if (rowok_ && (unsigned)gcol_ < 512u)                          \
                    v_ = *(const uint4*)(rowp_ + c_ * 4096 + gcol_ * 8);       \
            }                                                                  \
            rg[k] = v_;                                                        \
        }                                                                      \
    } while (0)

    #define STAGE_WRITE() do {                                                 \
        _Pragma("unroll")                                                      \
        for (int k = 0; k < 10; k++) {                                         \
            int f_ = t + k * 256;                                              \
            if (f_ < 2340) *(uint4*)(abuf + f_ * 8) = rg[k];                   \
        }                                                                      \
    } while (0)

    f32x16 acc00 = {}, acc01 = {}, acc10 = {}, acc11 = {};

    STAGE_LOAD(0);
    STAGE_WRITE();
    __syncthreads();

    #pragma unroll
    for (int di = 0; di < 3; di++) {
        if (di < 2) STAGE_LOAD(di + 1);
        #pragma unroll
        for (int dj = 0; dj < 3; dj++) {
            int tap = di * 3 + dj;
            const unsigned short* wt = wb + (size_t)(tap * 18 + lhi) * 1024 + (nt0 + l31) * 8;
            const unsigned short* ap0 = abuf + lhi * 1040 + (mt0 + l31 + dj) * 8;
            const unsigned short* ap1 = ap0 + 256;
            #pragma unroll
            for (int ksn = 0; ksn < 9; ksn++) {
                bf16x8 a0 = *(const bf16x8*)(ap0 + ksn * 2080);
                bf16x8 a1 = *(const bf16x8*)(ap1 + ksn * 2080);
                bf16x8 b0 = *(const bf16x8*)(wt + ksn * 2048);
                bf16x8 b1 = *(const bf16x8*)(wt + ksn * 2048 + 256);
                acc00 = __builtin_amdgcn_mfma_f32_32x32x16_bf16(a0, b0, acc00, 0, 0, 0);
                acc01 = __builtin_amdgcn_mfma_f32_32x32x16_bf16(a0, b1, acc01, 0, 0, 0);
                acc10 = __builtin_amdgcn_mfma_f32_32x32x16_bf16(a1, b0, acc10, 0, 0, 0);
                acc11 = __builtin_amdgcn_mfma_f32_32x32x16_bf16(a1, b1, acc11, 0, 0, 0);
            }
        }
        __syncthreads();
        if (di < 2) {
            STAGE_WRITE();
            __syncthreads();
        }
    }
    #undef STAGE_LOAD
    #undef STAGE_WRITE

    float* fb = (float*)abuf;
    #pragma unroll
    for (int mh = 0; mh < 2; mh++) {
        if ((w & 1) == mh) {
            #pragma unroll
            for (int mi = 0; mi < 2; mi++) {
                #pragma unroll
                for (int ni = 0; ni < 2; ni++) {
                    const f32x16* a = (mi == 0) ? (ni == 0 ? &acc00 : &acc01) : (ni == 0 ? &acc10 : &acc11);
                    int nb = nt0 + ni * 32 + l31;
                    float bA = csA[nb], b0_ = cs0[nb], b2_ = cs2[nb];
                    #pragma unroll
                    for (int r = 0; r < 16; r++) {
                        int ml = mi * 32 + 4 * lhi + (r & 3) + 8 * (r >> 2);
                        int j = j0 + mh * 64 + ml;
                        float bias = bA - (j == 0 ? b0_ : 0.f) - (j == 511 ? b2_ : 0.f);
                        float v = (*a)[r] + bias;
                        v = v >= 0.f ? v : 0.01f * v;
                        fb[ml * 128 + nb] = v;
                    }
                }
            }
        }
        __syncthreads();
        const float4* fb4 = (const float4*)fb;
        float4* gdst = (float4*)(pout + ((size_t)(i * 512 + j0 + mh * 64)) * 128);
        #pragma unroll
        for (int k = 0; k < 8; k++) {
            int f4i = k * 256 + t;
            gdst[f4i] = fb4[f4i];
        }
        __syncthreads();
    }
}

// ---------------------------------------------------------------- launcher
extern "C" void kernel_launch(void* const* d_in, const int* in_sizes, int n_in,
                              void* d_out, int out_size, void* d_ws, size_t ws_size,
                              hipStream_t stream) {
    (void)in_sizes; (void)n_in; (void)out_size; (void)ws_size;
    const float* R    = (const float*)d_in[0];
    const float* tv   = (const float*)d_in[1];
    const float* pcb  = (const float*)d_in[2];
    const float* x    = (const float*)d_in[3];
    const float* z    = (const float*)d_in[4];
    const float* wp2h = (const float*)d_in[5];
    const float* gamma= (const float*)d_in[6];
    const float* Wq   = (const float*)d_in[7];
    const float* Wk   = (const float*)d_in[8];
    const float* Wv   = (const float*)d_in[9];
    const float* W1   = (const float*)d_in[10];
    const float* b1   = (const float*)d_in[11];
    const float* ln1g = (const float*)d_in[12];
    const float* ln1b = (const float*)d_in[13];
    const float* W2   = (const float*)d_in[14];
    const float* b2   = (const float*)d_in[15];
    const float* caw  = (const float*)d_in[16];
    const float* cab  = (const float*)d_in[17];
    const float* lng  = (const float*)d_in[18];
    const float* lnb  = (const float*)d_in[19];
    const float* cpw  = (const float*)d_in[20];
    const float* cpb  = (const float*)d_in[21];

    float* ws = (float*)d_ws;
    float* qs     = ws;                 // 512*192
    float* ksv    = qs + 98304;
    float* vp     = ksv + 98304;
    float* q2     = vp + 98304;         // pad 4096
    float* k2     = q2 + 4096;
    float* lg_acc = k2 + 4096;          // 32
    float* lg_mr  = lg_acc + 32;        // 32
    float* pz_acc = lg_mr + 32;         // 272
    float* pz_mr  = pz_acc + 272;       // 272
    float* kc     = pz_mr + 272;        // 1152
    unsigned short* wbq = (unsigned short*)(kc + 1152);     // 165888 shorts (82944 floats)
    unsigned short* w1t = wbq + 165888;                     // 782336 shorts (391168 floats)
    float* lg     = kc + 1152 + 82944 + 391168;             // 16*LL
    float* alpha  = lg + 16 * LL;                           // 8*LL
    unsigned short* pzb = (unsigned short*)(alpha + 8 * LL);// 512*73728 bf16

    float* xout = (float*)d_out;
    float* pout = xout + 131072;

    hipLaunchKernelGGL(zero_stats_k, dim3(1), dim3(512), 0, stream, lg_acc, pz_acc);
    hipLaunchKernelGGL(w1t_prep_k, dim3(3056), dim3(256), 0, stream, W1, w1t);
    hipLaunchKernelGGL(qkv_k, dim3(512), dim3(256), 0, stream, x, Wq, Wk, Wv, R, tv, qs, ksv, vp, q2, k2);
    hipLaunchKernelGGL(zstats_pzb_k, dim3(2048), dim3(256), 0, stream, (const float4*)z, pz_acc, pzb);
    hipLaunchKernelGGL(lg_k, dim3(512), dim3(256), 0, stream, z, wp2h, gamma, qs, ksv, q2, k2, lg, lg_acc);
    hipLaunchKernelGGL(finalize_k, dim3(1), dim3(64), 0, stream, lg_acc, lg_mr, 16, 262144.f);
    hipLaunchKernelGGL(ca_softmax_k, dim3(512), dim3(256), 0, stream, lg, lg_mr, caw, cab, alpha, pz_acc, pzb);
    hipLaunchKernelGGL(finalize_k, dim3(1), dim3(192), 0, stream, pz_acc, pz_mr, 136, 262144.f);
    hipLaunchKernelGGL(wb_prep_k, dim3(648), dim3(256), 0, stream, cpw, pz_mr, wbq);
    hipLaunchKernelGGL(kc_prep_k, dim3(9), dim3(128), 0, stream, cpw, pz_mr, kc);
    hipLaunchKernelGGL(feat_mlp2_k, dim3(256), dim3(512), 0, stream,
                       alpha, z, vp, pcb, R, tv, w1t, b1, ln1g, ln1b, W2, b2, lng, lnb, x, xout);
    hipLaunchKernelGGL(conv_mfma_k, dim3(2048), dim3(256), 0, stream, pzb, wbq, kc, cpb, pout);
}